// Round 1
// baseline (390.591 us; speedup 1.0000x reference)
//
#include <hip/hip_runtime.h>
#include <stdint.h>

// Problem: B=8, S=1024, NX=1024, H=16, D=64 (GPT-2 attention block)
// out = [ a: B*S*NX ][ present_k: B*H*S*D ][ present_v: B*H*S*D ]
// Input/output dtype sniffed at runtime (fp32 vs bf16); internals bf16.

#define BB 8
#define SS 1024
#define NXX 1024
#define NH 16
#define HD 64

typedef __bf16 bf16x8 __attribute__((ext_vector_type(8)));
typedef float  floatx4 __attribute__((ext_vector_type(4)));
typedef unsigned short ushort8 __attribute__((ext_vector_type(8)));
typedef unsigned short ushortx4 __attribute__((ext_vector_type(4)));  // 'ushort4' collides with HIP builtin

__device__ inline float bf2f(unsigned short u) {
    unsigned int x = ((unsigned int)u) << 16;
    float f;
    __builtin_memcpy(&f, &x, 4);
    return f;
}
__device__ inline unsigned short f2bf(float f) {
    unsigned int u;
    __builtin_memcpy(&u, &f, 4);
    u += 0x7FFFu + ((u >> 16) & 1u);  // RNE
    return (unsigned short)(u >> 16);
}

// async global->LDS, 16B per lane (dest = wave-uniform base + lane*16)
__device__ inline void gload_lds16(const unsigned short* g, unsigned short* l) {
    __builtin_amdgcn_global_load_lds(
        (const __attribute__((address_space(1))) void*)g,
        (__attribute__((address_space(3))) void*)l, 16, 0, 0);
}

// ---------------- dtype sniff: flag=1 if data is fp32, 0 if bf16 ----------------
__global__ void sniff_k(const unsigned short* __restrict__ x, int* __restrict__ flag) {
    if (threadIdx.x == 0 && blockIdx.x == 0) {
        int g = 0;
        for (int i = 0; i < 512; i++) {
            float f = bf2f(x[i]);
            float a = fabsf(f);
            if (!(a <= 1e4f)) g++;
            else if (f != 0.f && a < 1e-35f) g++;
        }
        *flag = (g > 16) ? 1 : 0;
    }
}

// ---------------- prep: convert_x + transpose(Wqkv) + transpose(Wproj) ----------
// blocks [0,4096): xbf = bf16(x), 8 elems/thread
// blocks [4096,7168): WqkvT[3072][1024] = Wqkv[1024][3072]^T (bf16)
// blocks [7168,8192): WprojT[1024][1024] = Wproj^T (bf16)
__global__ __launch_bounds__(256) void prep(
    const void* __restrict__ x, const void* __restrict__ Wqkv,
    const void* __restrict__ Wproj,
    unsigned short* __restrict__ xbf, unsigned short* __restrict__ WqkvT,
    unsigned short* __restrict__ WprojT, const int* __restrict__ flagp) {
    const int f32 = *flagp;
    int blk = blockIdx.x;
    if (blk < 4096) {
        const size_t i = ((size_t)blk * 256 + threadIdx.x) * 8;
        if (f32) {
            const floatx4* p = (const floatx4*)((const float*)x + i);
            floatx4 f0 = p[0], f1 = p[1];
            ushort8 u;
#pragma unroll
            for (int j = 0; j < 4; j++) { u[j] = f2bf(f0[j]); u[4 + j] = f2bf(f1[j]); }
            *(ushort8*)(xbf + i) = u;
        } else {
            *(ushort8*)(xbf + i) = *(const ushort8*)((const unsigned short*)x + i);
        }
        return;
    }
    blk -= 4096;
    const void* in;
    unsigned short* out;
    int R, C;
    if (blk < 3072) { in = Wqkv; out = WqkvT; R = 1024; C = 3072; }
    else            { blk -= 3072; in = Wproj; out = WprojT; R = 1024; C = 1024; }
    const int ctiles = C / 32;
    const int c0 = (blk % ctiles) * 32, r0 = (blk / ctiles) * 32;

    __shared__ unsigned short tile[32][33];
    const int tx = threadIdx.x & 31, ty = threadIdx.x >> 5;  // 32 x 8
    if (f32) {
        const float* inf = (const float*)in;
#pragma unroll
        for (int i = ty; i < 32; i += 8)
            tile[i][tx] = f2bf(inf[(size_t)(r0 + i) * C + c0 + tx]);
    } else {
        const unsigned short* inu = (const unsigned short*)in;
#pragma unroll
        for (int i = ty; i < 32; i += 8)
            tile[i][tx] = inu[(size_t)(r0 + i) * C + c0 + tx];
    }
    __syncthreads();
#pragma unroll
    for (int i = ty; i < 32; i += 8)
        out[(size_t)(c0 + i) * R + r0 + tx] = tile[tx][i];
}

// ---------------- transpose_v: vbfT[bh][d][sperm] <- d_out v region ------------
// One block per (bh, 64-s block). sperm within 64: ((s&15)<<2)|(s>>4).
__global__ __launch_bounds__(256) void transpose_v(
    const void* __restrict__ outbase, unsigned short* __restrict__ vbfT,
    const int* __restrict__ flagp) {
    const int f32 = *flagp;
    const int blk = blockIdx.x;
    const int sb = blk & 15;       // which 64-s block
    const int bh = blk >> 4;       // 0..127
    const int tid = threadIdx.x;
    const int r = tid >> 2;          // s within 64-block
    const int c0 = (tid & 3) * 16;   // d start
    __shared__ unsigned short tile[64][72];
    const int perm = ((r & 15) << 2) | (r >> 4);
    const size_t esz = f32 ? 4 : 2;
    const char* vbase = (const char*)outbase + (size_t)(2 * BB * SS * NXX) * esz;
    if (f32) {
        const float* src = (const float*)vbase + ((size_t)bh * SS + sb * 64 + r) * HD + c0;
#pragma unroll
        for (int j = 0; j < 16; j++) tile[c0 + j][perm] = f2bf(src[j]);
    } else {
        const unsigned short* src = (const unsigned short*)vbase + ((size_t)bh * SS + sb * 64 + r) * HD + c0;
#pragma unroll
        for (int j = 0; j < 16; j++) tile[c0 + j][perm] = src[j];
    }
    __syncthreads();
    const int d = tid >> 2;
    const int o0 = (tid & 3) * 16;
    unsigned short* dst = vbfT + ((size_t)(bh * HD + d)) * SS + sb * 64 + o0;
    *(ushort8*)dst       = *(const ushort8*)&tile[d][o0];
    *(ushort8*)(dst + 8) = *(const ushort8*)&tile[d][o0 + 8];
}

// ---------------- GEMM: C[M,N] = A[M,K] @ Bt[N,K]^T + bias[N] ----------------
// A, Bt: bf16. Staging via global_load_lds (16B/lane), double-buffered LDS,
// prefetch issued BEFORE compute (T3-minimum 2-phase: stage latency hides
// under ds_read+MFMA; single __syncthreads per K-step).
// MODE 0: writes `a` region of d_out in flag dtype.
// MODE 1: block-uniform section (col0>>10): q->q_ws bf16; k->d_out+kbf; v->d_out.
template <int MODE>
__global__ __launch_bounds__(256) void gemm_bt(
    const unsigned short* __restrict__ A,
    const unsigned short* __restrict__ Bt,
    const void* __restrict__ bias,
    void* __restrict__ outbase,
    unsigned short* __restrict__ q_ws,
    unsigned short* __restrict__ kbf,
    int M, int N, int K, const int* __restrict__ flagp) {
    __shared__ __align__(16) unsigned short As[2][128 * 32];
    __shared__ __align__(16) unsigned short Bs[2][128 * 32];

    const int f32 = *flagp;
    const int tid  = threadIdx.x;
    const int lane = tid & 63;
    const int wave = tid >> 6;
    const int wr = wave >> 1, wc = wave & 1;
    const int l15 = lane & 15;
    const int quad = lane >> 4;
    const int row0 = blockIdx.y * 128;
    const int col0 = blockIdx.x * 128;

    floatx4 acc[4][4];
    floatx4 zz = {0.f, 0.f, 0.f, 0.f};
#pragma unroll
    for (int i = 0; i < 4; i++)
#pragma unroll
        for (int j = 0; j < 4; j++) acc[i][j] = zz;

    const int lrow = lane >> 2;
    const int lcol = (lane & 3) * 8;
    const unsigned short* Ag = A  + (size_t)(row0 + wave * 32 + lrow) * K + lcol;
    const unsigned short* Bg = Bt + (size_t)(col0 + wave * 32 + lrow) * K + lcol;
    const int sl0 = (wave * 32) * 32;
    const int sl1 = (wave * 32 + 16) * 32;

    // prologue: stage tile 0 into buffer 0
    gload_lds16(Ag, &As[0][sl0]);
    gload_lds16(Ag + (size_t)16 * K, &As[0][sl1]);
    gload_lds16(Bg, &Bs[0][sl0]);
    gload_lds16(Bg + (size_t)16 * K, &Bs[0][sl1]);
    __syncthreads();

    int cur = 0;
    for (int k0 = 0; k0 < K; k0 += 32) {
        // issue next-tile prefetch into the other buffer BEFORE compute
        if (k0 + 32 < K) {
            const unsigned short* Agn = Ag + k0 + 32;
            const unsigned short* Bgn = Bg + k0 + 32;
            gload_lds16(Agn, &As[cur ^ 1][sl0]);
            gload_lds16(Agn + (size_t)16 * K, &As[cur ^ 1][sl1]);
            gload_lds16(Bgn, &Bs[cur ^ 1][sl0]);
            gload_lds16(Bgn + (size_t)16 * K, &Bs[cur ^ 1][sl1]);
        }

        bf16x8 af[4], bfr[4];
#pragma unroll
        for (int mi = 0; mi < 4; mi++)
            af[mi] = *(const bf16x8*)&As[cur][(wr * 64 + mi * 16 + l15) * 32 + quad * 8];
#pragma unroll
        for (int ni = 0; ni < 4; ni++)
            bfr[ni] = *(const bf16x8*)&Bs[cur][(wc * 64 + ni * 16 + l15) * 32 + quad * 8];
#pragma unroll
        for (int mi = 0; mi < 4; mi++)
#pragma unroll
            for (int ni = 0; ni < 4; ni++)
                acc[mi][ni] = __builtin_amdgcn_mfma_f32_16x16x32_bf16(af[mi], bfr[ni], acc[mi][ni], 0, 0, 0);

        // barrier drains vmcnt(0): prefetch had the whole compute phase to land
        __syncthreads();
        cur ^= 1;
    }

    float bv[4];
#pragma unroll
    for (int ni = 0; ni < 4; ni++) {
        const int colb = col0 + wc * 64 + ni * 16 + l15;
        bv[ni] = f32 ? ((const float*)bias)[colb] : bf2f(((const unsigned short*)bias)[colb]);
    }

    if (MODE == 0) {
#pragma unroll
        for (int mi = 0; mi < 4; mi++)
#pragma unroll
            for (int ni = 0; ni < 4; ni++) {
                const int colb = col0 + wc * 64 + ni * 16 + l15;
#pragma unroll
                for (int i = 0; i < 4; i++) {
                    const int row = row0 + wr * 64 + mi * 16 + quad * 4 + i;
                    const float val = acc[mi][ni][i] + bv[ni];
                    const size_t idx = (size_t)row * N + colb;
                    if (f32) ((float*)outbase)[idx] = val;
                    else     ((unsigned short*)outbase)[idx] = f2bf(val);
                }
            }
        return;
    }

    // MODE 1: section is block-uniform (col tile never straddles 1024 boundary)
    const int sec = col0 >> 10;
    const size_t esz = f32 ? 4 : 2;
    const int b = row0 >> 10;
    const int s0 = row0 & 1023;

    if (sec == 0) {
#pragma unroll
        for (int mi = 0; mi < 4; mi++)
#pragma unroll
            for (int ni = 0; ni < 4; ni++) {
                const int colb = col0 + wc * 64 + ni * 16 + l15;
                const int h = (colb & 1023) >> 6, d = colb & 63;
#pragma unroll
                for (int i = 0; i < 4; i++) {
                    const int s = s0 + wr * 64 + mi * 16 + quad * 4 + i;
                    q_ws[(size_t)((b * NH + h) * SS + s) * HD + d] = f2bf(acc[mi][ni][i] + bv[ni]);
                }
            }
    } else if (sec == 1) {
        char* kbase = (char*)outbase + (size_t)(BB * SS * NXX) * esz;
#pragma unroll
        for (int mi = 0; mi < 4; mi++)
#pragma unroll
            for (int ni = 0; ni < 4; ni++) {
                const int colb = col0 + wc * 64 + ni * 16 + l15;
                const int h = (colb & 1023) >> 6, d = colb & 63;
#pragma unroll
                for (int i = 0; i < 4; i++) {
                    const int s = s0 + wr * 64 + mi * 16 + quad * 4 + i;
                    const float val = acc[mi][ni][i] + bv[ni];
                    const size_t idx = (size_t)((b * NH + h) * SS + s) * HD + d;
                    if (f32) ((float*)kbase)[idx] = val;
                    else     ((unsigned short*)kbase)[idx] = f2bf(val);
                    kbf[idx] = f2bf(val);
                }
            }
    } else {
        char* vbase = (char*)outbase + (size_t)(2 * BB * SS * NXX) * esz;
#pragma unroll
        for (int mi = 0; mi < 4; mi++)
#pragma unroll
            for (int ni = 0; ni < 4; ni++) {
                const int colb = col0 + wc * 64 + ni * 16 + l15;
                const int h = (colb & 1023) >> 6, d = colb & 63;
#pragma unroll
                for (int i = 0; i < 4; i++) {
                    const int s = s0 + wr * 64 + mi * 16 + quad * 4 + i;
                    const float val = acc[mi][ni][i] + bv[ni];
                    const size_t idx = (size_t)((b * NH + h) * SS + s) * HD + d;
                    if (f32) ((float*)vbase)[idx] = val;
                    else     ((unsigned short*)vbase)[idx] = f2bf(val);
                }
            }
    }
}

// ---------------- flash attention: 4 waves/block, 2 paired Q-tiles/block ----------
// q_ws/kbf: [bh][s][d] bf16; vbfT: [bh][d][s] bf16 (key-permuted); amerged bf16.
// K/V fragments are loaded DIRECTLY from global (L2-resident at S=1024;
// LDS staging was pure overhead — guide common-mistake #7 / m169).
// Only LDS use is the wave-private P bounce (Pl[w]) -> kernel is barrier-free.
__global__ __launch_bounds__(256) void attn(
    const unsigned short* __restrict__ q_ws,
    const unsigned short* __restrict__ kbf,
    const unsigned short* __restrict__ vbfT,
    unsigned short* __restrict__ amerged) {
    const int tid = threadIdx.x;
    const int lane = tid & 63;
    const int w = tid >> 6;
    const int l15 = lane & 15, quad = lane >> 4;
    const int blk = blockIdx.x;
    const int p = blk & 3;               // tile pair: {p, 7-p} (balanced: 18 units each)
    const int bh = blk >> 2;
    const int b = bh >> 4, h = bh & 15;

    const unsigned short* Q = q_ws + (size_t)bh * (SS * HD);
    const unsigned short* K = kbf + (size_t)bh * (SS * HD);
    const unsigned short* V = vbfT + (size_t)bh * (HD * SS);

    __shared__ __align__(16) unsigned short Pl[4][32][72];

    floatx4 zz = {0.f, 0.f, 0.f, 0.f};
    ushort8 ones_u;
#pragma unroll
    for (int j = 0; j < 8; j++) ones_u[j] = 0x3F80;  // bf16 1.0
    const bf16x8 ones = __builtin_bit_cast(bf16x8, ones_u);

#pragma unroll
    for (int tile = 0; tile < 2; tile++) {
        const int qb = tile ? (7 - p) : p;
        const int wrow0 = qb * 128 + w * 32;
        const int wq_max = wrow0 + 31;

        bf16x8 qa[2][2];
#pragma unroll
        for (int m = 0; m < 2; m++)
#pragma unroll
            for (int t = 0; t < 2; t++)
                qa[m][t] = *(const bf16x8*)&Q[(size_t)(wrow0 + m * 16 + l15) * HD + t * 32 + quad * 8];

        floatx4 o[2][4], o5[2];
        float mrow[2][4];
#pragma unroll
        for (int m = 0; m < 2; m++) {
            o5[m] = zz;
#pragma unroll
            for (int i = 0; i < 4; i++) mrow[m][i] = -1e30f;
#pragma unroll
            for (int nf = 0; nf < 4; nf++) o[m][nf] = zz;
        }

        // per-wave loop: each wave stops at its own causal frontier
        for (int j0 = 0; j0 <= wq_max; j0 += 64) {
            // QK^T: K fragments direct from global (row-major [s][d])
            floatx4 sf[2][4];
#pragma unroll
            for (int kg = 0; kg < 4; kg++) {
                const size_t krow = (size_t)(j0 + kg * 16 + l15) * HD;
                bf16x8 kb0 = *(const bf16x8*)&K[krow + quad * 8];
                bf16x8 kb1 = *(const bf16x8*)&K[krow + 32 + quad * 8];
#pragma unroll
                for (int m = 0; m < 2; m++) {
                    floatx4 s = zz;
                    s = __builtin_amdgcn_mfma_f32_16x16x32_bf16(qa[m][0], kb0, s, 0, 0, 0);
                    s = __builtin_amdgcn_mfma_f32_16x16x32_bf16(qa[m][1], kb1, s, 0, 0, 0);
                    sf[m][kg] = s;
                }
            }

            float alpha_[2][4];
#pragma unroll
            for (int m = 0; m < 2; m++)
#pragma unroll
                for (int i = 0; i < 4; i++) {
                    const int qrow = wrow0 + m * 16 + quad * 4 + i;
                    float pv4[4];
#pragma unroll
                    for (int kg = 0; kg < 4; kg++) {
                        const int key = j0 + kg * 16 + l15;
                        float s = sf[m][kg][i] * 0.125f;
                        if (key > qrow) s = -10000.0f;
                        pv4[kg] = s;
                    }
                    float t = fmaxf(fmaxf(pv4[0], pv4[1]), fmaxf(pv4[2], pv4[3]));
                    t = fmaxf(t, __shfl_xor(t, 1));
                    t = fmaxf(t, __shfl_xor(t, 2));
                    t = fmaxf(t, __shfl_xor(t, 4));
                    t = fmaxf(t, __shfl_xor(t, 8));
                    const float mnew = fmaxf(mrow[m][i], t);
                    alpha_[m][i] = __expf(mrow[m][i] - mnew);
                    mrow[m][i] = mnew;
                    ushortx4 pk;
#pragma unroll
                    for (int kg = 0; kg < 4; kg++)
                        pk[kg] = f2bf(__expf(pv4[kg] - mnew));
                    *(ushortx4*)&Pl[w][m * 16 + quad * 4 + i][l15 * 4] = pk;
                }

            // rescale running state while the Pl ds_writes land
#pragma unroll
            for (int m = 0; m < 2; m++) {
#pragma unroll
                for (int i = 0; i < 4; i++) o5[m][i] *= alpha_[m][i];
#pragma unroll
                for (int nf = 0; nf < 4; nf++)
#pragma unroll
                    for (int i = 0; i < 4; i++) o[m][nf][i] *= alpha_[m][i];
            }

            // in-wave ds_write -> ds_read ordering (no cross-wave barrier needed:
            // Pl[w] is wave-private; DS ops per wave execute in order).
            asm volatile("s_waitcnt lgkmcnt(0)" ::: "memory");
            __builtin_amdgcn_sched_barrier(0);

            bf16x8 pa[2][2];
#pragma unroll
            for (int m = 0; m < 2; m++) {
                pa[m][0] = *(const bf16x8*)&Pl[w][m * 16 + l15][quad * 8];
                pa[m][1] = *(const bf16x8*)&Pl[w][m * 16 + l15][32 + quad * 8];
            }

#pragma unroll
            for (int m = 0; m < 2; m++) {
                o5[m] = __builtin_amdgcn_mfma_f32_16x16x32_bf16(pa[m][0], ones, o5[m], 0, 0, 0);
                o5[m] = __builtin_amdgcn_mfma_f32_16x16x32_bf16(pa[m][1], ones, o5[m], 0, 0, 0);
            }
            // PV: V^T fragments direct from global ([d][s], key-permuted to match Pl)
#pragma unroll
            for (int nf = 0; nf < 4; nf++) {
                const size_t vrow = (size_t)(nf * 16 + l15) * SS + j0;
                bf16x8 vb0 = *(const bf16x8*)&V[vrow + quad * 8];
                bf16x8 vb1 = *(const bf16x8*)&V[vrow + 32 + quad * 8];
#pragma unroll
                for (int m = 0; m < 2; m++) {
                    o[m][nf] = __builtin_amdgcn_mfma_f32_16x16x32_bf16(pa[m][0], vb0, o[m][nf], 0, 0, 0);
                    o[m][nf] = __builtin_amdgcn_mfma_f32_16x16x32_bf16(pa[m][1], vb1, o[m][nf], 0, 0, 0);
                }
            }
        }

#pragma unroll
        for (int m = 0; m < 2; m++)
#pragma unroll
            for (int nf = 0; nf < 4; nf++)
#pragma unroll
                for (int i = 0; i < 4; i++) {
                    const int s = wrow0 + m * 16 + quad * 4 + i;
                    amerged[(size_t)(b * SS + s) * NXX + h * HD + nf * 16 + l15] =
                        f2bf(o[m][nf][i] / o5[m][i]);
                }
    }
}

extern "C" void kernel_launch(void* const* d_in, const int* in_sizes, int n_in,
                              void* d_out, int out_size, void* d_ws, size_t ws_size,
                              hipStream_t stream) {
    const void* x     = d_in[0];
    const void* Wqkv  = d_in[1];
    const void* bqkv  = d_in[2];
    const void* Wproj = d_in[3];
    const void* bproj = d_in[4];

    int* flag = (int*)d_ws;
    unsigned short* ws = (unsigned short*)d_ws + 8;
    unsigned short* WqkvT   = ws;                        // 3072*1024  (6 MB)
    unsigned short* WprojT  = WqkvT + 3072 * 1024;       // 1024*1024  (2 MB)
    unsigned short* q_ws    = WprojT + 1024 * 1024;      // 8M         (16 MB)
    unsigned short* kbf     = q_ws + 8 * 1024 * 1024;    // 8M         (16 MB)
    unsigned short* vbfT    = kbf + 8 * 1024 * 1024;     // 8M         (16 MB)
    unsigned short* amerged = vbfT + 8 * 1024 * 1024;    // 8M         (16 MB)
    unsigned short* xbf     = amerged;                   // ALIAS: xbf dead before attn writes amerged
    // total ws: ~72 MB

    sniff_k<<<1, 64, 0, stream>>>((const unsigned short*)x, flag);
    prep<<<dim3(8192), 256, 0, stream>>>(x, Wqkv, Wproj, xbf, WqkvT, WprojT, flag);
    gemm_bt<1><<<dim3(3072 / 128, 8192 / 128), 256, 0, stream>>>(
        xbf, WqkvT, bqkv, d_out, q_ws, kbf, 8192, 3072, 1024, flag);
    transpose_v<<<dim3(128 * 16), 256, 0, stream>>>(d_out, vbfT, flag);
    attn<<<dim3(BB * NH * 4), 256, 0, stream>>>(q_ws, kbf, vbfT, amerged);
    gemm_bt<0><<<dim3(1024 / 128, 8192 / 128), 256, 0, stream>>>(
        amerged, WprojT, bproj, d_out, nullptr, nullptr, 8192, 1024, 1024, flag);
}

// Round 2
// 359.014 us; speedup vs baseline: 1.0880x; 1.0880x over previous
//
#include <hip/hip_runtime.h>
#include <stdint.h>

// Problem: B=8, S=1024, NX=1024, H=16, D=64 (GPT-2 attention block)
// out = [ a: B*S*NX ][ present_k: B*H*S*D ][ present_v: B*H*S*D ]
// Input/output dtype sniffed at runtime (fp32 vs bf16); internals bf16.

#define BB 8
#define SS 1024
#define NXX 1024
#define NH 16
#define HD 64

typedef __bf16 bf16x8 __attribute__((ext_vector_type(8)));
typedef float  floatx4 __attribute__((ext_vector_type(4)));
typedef unsigned short ushort8 __attribute__((ext_vector_type(8)));
typedef unsigned short ushortx4 __attribute__((ext_vector_type(4)));  // 'ushort4' collides with HIP builtin

__device__ inline float bf2f(unsigned short u) {
    unsigned int x = ((unsigned int)u) << 16;
    float f;
    __builtin_memcpy(&f, &x, 4);
    return f;
}
__device__ inline unsigned short f2bf(float f) {
    unsigned int u;
    __builtin_memcpy(&u, &f, 4);
    u += 0x7FFFu + ((u >> 16) & 1u);  // RNE
    return (unsigned short)(u >> 16);
}

// async global->LDS, 16B per lane (dest = wave-uniform base + lane*16)
__device__ inline void gload_lds16(const unsigned short* g, unsigned short* l) {
    __builtin_amdgcn_global_load_lds(
        (const __attribute__((address_space(1))) void*)g,
        (__attribute__((address_space(3))) void*)l, 16, 0, 0);
}

// ---------------- dtype sniff: flag=1 if data is fp32, 0 if bf16 ----------------
__global__ void sniff_k(const unsigned short* __restrict__ x, int* __restrict__ flag) {
    if (threadIdx.x == 0 && blockIdx.x == 0) {
        int g = 0;
        for (int i = 0; i < 512; i++) {
            float f = bf2f(x[i]);
            float a = fabsf(f);
            if (!(a <= 1e4f)) g++;
            else if (f != 0.f && a < 1e-35f) g++;
        }
        *flag = (g > 16) ? 1 : 0;
    }
}

// ---------------- prep: convert_x + transpose(Wqkv) + transpose(Wproj) ----------
// blocks [0,4096): xbf = bf16(x), 8 elems/thread
// blocks [4096,7168): WqkvT[3072][1024] = Wqkv[1024][3072]^T (bf16)
// blocks [7168,8192): WprojT[1024][1024] = Wproj^T (bf16)
__global__ __launch_bounds__(256) void prep(
    const void* __restrict__ x, const void* __restrict__ Wqkv,
    const void* __restrict__ Wproj,
    unsigned short* __restrict__ xbf, unsigned short* __restrict__ WqkvT,
    unsigned short* __restrict__ WprojT, const int* __restrict__ flagp) {
    const int f32 = *flagp;
    int blk = blockIdx.x;
    if (blk < 4096) {
        const size_t i = ((size_t)blk * 256 + threadIdx.x) * 8;
        if (f32) {
            const floatx4* p = (const floatx4*)((const float*)x + i);
            floatx4 f0 = p[0], f1 = p[1];
            ushort8 u;
#pragma unroll
            for (int j = 0; j < 4; j++) { u[j] = f2bf(f0[j]); u[4 + j] = f2bf(f1[j]); }
            *(ushort8*)(xbf + i) = u;
        } else {
            *(ushort8*)(xbf + i) = *(const ushort8*)((const unsigned short*)x + i);
        }
        return;
    }
    blk -= 4096;
    const void* in;
    unsigned short* out;
    int R, C;
    if (blk < 3072) { in = Wqkv; out = WqkvT; R = 1024; C = 3072; }
    else            { blk -= 3072; in = Wproj; out = WprojT; R = 1024; C = 1024; }
    const int ctiles = C / 32;
    const int c0 = (blk % ctiles) * 32, r0 = (blk / ctiles) * 32;

    __shared__ unsigned short tile[32][33];
    const int tx = threadIdx.x & 31, ty = threadIdx.x >> 5;  // 32 x 8
    if (f32) {
        const float* inf = (const float*)in;
#pragma unroll
        for (int i = ty; i < 32; i += 8)
            tile[i][tx] = f2bf(inf[(size_t)(r0 + i) * C + c0 + tx]);
    } else {
        const unsigned short* inu = (const unsigned short*)in;
#pragma unroll
        for (int i = ty; i < 32; i += 8)
            tile[i][tx] = inu[(size_t)(r0 + i) * C + c0 + tx];
    }
    __syncthreads();
#pragma unroll
    for (int i = ty; i < 32; i += 8)
        out[(size_t)(c0 + i) * R + r0 + tx] = tile[tx][i];
}

// ---------------- transpose_v: vbfT[bh][d][sperm] <- d_out v region ------------
// One block per (bh, 64-s block). sperm within 64: ((s&15)<<2)|(s>>4).
__global__ __launch_bounds__(256) void transpose_v(
    const void* __restrict__ outbase, unsigned short* __restrict__ vbfT,
    const int* __restrict__ flagp) {
    const int f32 = *flagp;
    const int blk = blockIdx.x;
    const int sb = blk & 15;       // which 64-s block
    const int bh = blk >> 4;       // 0..127
    const int tid = threadIdx.x;
    const int r = tid >> 2;          // s within 64-block
    const int c0 = (tid & 3) * 16;   // d start
    __shared__ unsigned short tile[64][72];
    const int perm = ((r & 15) << 2) | (r >> 4);
    const size_t esz = f32 ? 4 : 2;
    const char* vbase = (const char*)outbase + (size_t)(2 * BB * SS * NXX) * esz;
    if (f32) {
        const float* src = (const float*)vbase + ((size_t)bh * SS + sb * 64 + r) * HD + c0;
#pragma unroll
        for (int j = 0; j < 16; j++) tile[c0 + j][perm] = f2bf(src[j]);
    } else {
        const unsigned short* src = (const unsigned short*)vbase + ((size_t)bh * SS + sb * 64 + r) * HD + c0;
#pragma unroll
        for (int j = 0; j < 16; j++) tile[c0 + j][perm] = src[j];
    }
    __syncthreads();
    const int d = tid >> 2;
    const int o0 = (tid & 3) * 16;
    unsigned short* dst = vbfT + ((size_t)(bh * HD + d)) * SS + sb * 64 + o0;
    *(ushort8*)dst       = *(const ushort8*)&tile[d][o0];
    *(ushort8*)(dst + 8) = *(const ushort8*)&tile[d][o0 + 8];
}

// ---------------- GEMM: C[M,N] = A[M,K] @ Bt[N,K]^T + bias[N] ----------------
// A, Bt: bf16. Staging via global_load_lds (16B/lane), double-buffered LDS,
// prefetch issued BEFORE compute (T3-minimum 2-phase: stage latency hides
// under ds_read+MFMA; single __syncthreads per K-step).
// MODE 0: writes `a` region of d_out in flag dtype.
// MODE 1: block-uniform section (col0>>10): q->q_ws bf16; k->d_out+kbf; v->d_out.
template <int MODE>
__global__ __launch_bounds__(256) void gemm_bt(
    const unsigned short* __restrict__ A,
    const unsigned short* __restrict__ Bt,
    const void* __restrict__ bias,
    void* __restrict__ outbase,
    unsigned short* __restrict__ q_ws,
    unsigned short* __restrict__ kbf,
    int M, int N, int K, const int* __restrict__ flagp) {
    __shared__ __align__(16) unsigned short As[2][128 * 32];
    __shared__ __align__(16) unsigned short Bs[2][128 * 32];

    const int f32 = *flagp;
    const int tid  = threadIdx.x;
    const int lane = tid & 63;
    const int wave = tid >> 6;
    const int wr = wave >> 1, wc = wave & 1;
    const int l15 = lane & 15;
    const int quad = lane >> 4;
    const int row0 = blockIdx.y * 128;
    const int col0 = blockIdx.x * 128;

    floatx4 acc[4][4];
    floatx4 zz = {0.f, 0.f, 0.f, 0.f};
#pragma unroll
    for (int i = 0; i < 4; i++)
#pragma unroll
        for (int j = 0; j < 4; j++) acc[i][j] = zz;

    const int lrow = lane >> 2;
    const int lcol = (lane & 3) * 8;
    const unsigned short* Ag = A  + (size_t)(row0 + wave * 32 + lrow) * K + lcol;
    const unsigned short* Bg = Bt + (size_t)(col0 + wave * 32 + lrow) * K + lcol;
    const int sl0 = (wave * 32) * 32;
    const int sl1 = (wave * 32 + 16) * 32;

    // prologue: stage tile 0 into buffer 0
    gload_lds16(Ag, &As[0][sl0]);
    gload_lds16(Ag + (size_t)16 * K, &As[0][sl1]);
    gload_lds16(Bg, &Bs[0][sl0]);
    gload_lds16(Bg + (size_t)16 * K, &Bs[0][sl1]);
    __syncthreads();

    int cur = 0;
    for (int k0 = 0; k0 < K; k0 += 32) {
        // issue next-tile prefetch into the other buffer BEFORE compute
        if (k0 + 32 < K) {
            const unsigned short* Agn = Ag + k0 + 32;
            const unsigned short* Bgn = Bg + k0 + 32;
            gload_lds16(Agn, &As[cur ^ 1][sl0]);
            gload_lds16(Agn + (size_t)16 * K, &As[cur ^ 1][sl1]);
            gload_lds16(Bgn, &Bs[cur ^ 1][sl0]);
            gload_lds16(Bgn + (size_t)16 * K, &Bs[cur ^ 1][sl1]);
        }

        bf16x8 af[4], bfr[4];
#pragma unroll
        for (int mi = 0; mi < 4; mi++)
            af[mi] = *(const bf16x8*)&As[cur][(wr * 64 + mi * 16 + l15) * 32 + quad * 8];
#pragma unroll
        for (int ni = 0; ni < 4; ni++)
            bfr[ni] = *(const bf16x8*)&Bs[cur][(wc * 64 + ni * 16 + l15) * 32 + quad * 8];
#pragma unroll
        for (int mi = 0; mi < 4; mi++)
#pragma unroll
            for (int ni = 0; ni < 4; ni++)
                acc[mi][ni] = __builtin_amdgcn_mfma_f32_16x16x32_bf16(af[mi], bfr[ni], acc[mi][ni], 0, 0, 0);

        // barrier drains vmcnt(0): prefetch had the whole compute phase to land
        __syncthreads();
        cur ^= 1;
    }

    float bv[4];
#pragma unroll
    for (int ni = 0; ni < 4; ni++) {
        const int colb = col0 + wc * 64 + ni * 16 + l15;
        bv[ni] = f32 ? ((const float*)bias)[colb] : bf2f(((const unsigned short*)bias)[colb]);
    }

    if (MODE == 0) {
#pragma unroll
        for (int mi = 0; mi < 4; mi++)
#pragma unroll
            for (int ni = 0; ni < 4; ni++) {
                const int colb = col0 + wc * 64 + ni * 16 + l15;
#pragma unroll
                for (int i = 0; i < 4; i++) {
                    const int row = row0 + wr * 64 + mi * 16 + quad * 4 + i;
                    const float val = acc[mi][ni][i] + bv[ni];
                    const size_t idx = (size_t)row * N + colb;
                    if (f32) ((float*)outbase)[idx] = val;
                    else     ((unsigned short*)outbase)[idx] = f2bf(val);
                }
            }
        return;
    }

    // MODE 1: section is block-uniform (col tile never straddles 1024 boundary)
    const int sec = col0 >> 10;
    const size_t esz = f32 ? 4 : 2;
    const int b = row0 >> 10;
    const int s0 = row0 & 1023;

    if (sec == 0) {
#pragma unroll
        for (int mi = 0; mi < 4; mi++)
#pragma unroll
            for (int ni = 0; ni < 4; ni++) {
                const int colb = col0 + wc * 64 + ni * 16 + l15;
                const int h = (colb & 1023) >> 6, d = colb & 63;
#pragma unroll
                for (int i = 0; i < 4; i++) {
                    const int s = s0 + wr * 64 + mi * 16 + quad * 4 + i;
                    q_ws[(size_t)((b * NH + h) * SS + s) * HD + d] = f2bf(acc[mi][ni][i] + bv[ni]);
                }
            }
    } else if (sec == 1) {
        char* kbase = (char*)outbase + (size_t)(BB * SS * NXX) * esz;
#pragma unroll
        for (int mi = 0; mi < 4; mi++)
#pragma unroll
            for (int ni = 0; ni < 4; ni++) {
                const int colb = col0 + wc * 64 + ni * 16 + l15;
                const int h = (colb & 1023) >> 6, d = colb & 63;
#pragma unroll
                for (int i = 0; i < 4; i++) {
                    const int s = s0 + wr * 64 + mi * 16 + quad * 4 + i;
                    const float val = acc[mi][ni][i] + bv[ni];
                    const size_t idx = (size_t)((b * NH + h) * SS + s) * HD + d;
                    if (f32) ((float*)kbase)[idx] = val;
                    else     ((unsigned short*)kbase)[idx] = f2bf(val);
                    kbf[idx] = f2bf(val);
                }
            }
    } else {
        char* vbase = (char*)outbase + (size_t)(2 * BB * SS * NXX) * esz;
#pragma unroll
        for (int mi = 0; mi < 4; mi++)
#pragma unroll
            for (int ni = 0; ni < 4; ni++) {
                const int colb = col0 + wc * 64 + ni * 16 + l15;
                const int h = (colb & 1023) >> 6, d = colb & 63;
#pragma unroll
                for (int i = 0; i < 4; i++) {
                    const int s = s0 + wr * 64 + mi * 16 + quad * 4 + i;
                    const float val = acc[mi][ni][i] + bv[ni];
                    const size_t idx = (size_t)((b * NH + h) * SS + s) * HD + d;
                    if (f32) ((float*)vbase)[idx] = val;
                    else     ((unsigned short*)vbase)[idx] = f2bf(val);
                }
            }
    }
}

// ---------------- flash attention: 4 waves/block, 2 paired Q-tiles/block ----------
// q_ws/kbf: [bh][s][d] bf16; vbfT: [bh][d][s] bf16 (key-permuted); amerged bf16.
// LDS-staged K/V with register prefetch of the next 64-key tile (this IS a
// working 2-deep pipeline; round-1's direct-global variant regressed ~40us).
__global__ __launch_bounds__(256) void attn(
    const unsigned short* __restrict__ q_ws,
    const unsigned short* __restrict__ kbf,
    const unsigned short* __restrict__ vbfT,
    unsigned short* __restrict__ amerged) {
    const int tid = threadIdx.x;
    const int lane = tid & 63;
    const int w = tid >> 6;
    const int l15 = lane & 15, quad = lane >> 4;
    const int blk = blockIdx.x;
    const int p = blk & 3;               // tile pair: {p, 7-p} (balanced: 18 units each)
    const int bh = blk >> 2;
    const int b = bh >> 4, h = bh & 15;

    const unsigned short* Q = q_ws + (size_t)bh * (SS * HD);
    const unsigned short* K = kbf + (size_t)bh * (SS * HD);
    const unsigned short* V = vbfT + (size_t)bh * (HD * SS);

    __shared__ __align__(16) unsigned short Ks[64][72];
    __shared__ __align__(16) unsigned short Vs[64][72];
    __shared__ __align__(16) unsigned short Pl[4][32][72];

    floatx4 zz = {0.f, 0.f, 0.f, 0.f};
    ushort8 ones_u;
#pragma unroll
    for (int j = 0; j < 8; j++) ones_u[j] = 0x3F80;  // bf16 1.0
    const bf16x8 ones = __builtin_bit_cast(bf16x8, ones_u);

    const int srow = tid >> 2;           // 0..63
    const int soff = (tid & 3) * 16;     // 0/16/32/48

#pragma unroll
    for (int tile = 0; tile < 2; tile++) {
        const int qb = tile ? (7 - p) : p;
        const int qbase = qb * 128;
        const int wrow0 = qbase + w * 32;
        const int wq_max = wrow0 + 31;
        const int jend = qbase + 128;

        bf16x8 qa[2][2];
#pragma unroll
        for (int m = 0; m < 2; m++)
#pragma unroll
            for (int t = 0; t < 2; t++)
                qa[m][t] = *(const bf16x8*)&Q[(size_t)(wrow0 + m * 16 + l15) * HD + t * 32 + quad * 8];

        floatx4 o[2][4], o5[2];
        float mrow[2][4];
#pragma unroll
        for (int m = 0; m < 2; m++) {
            o5[m] = zz;
#pragma unroll
            for (int i = 0; i < 4; i++) mrow[m][i] = -1e30f;
#pragma unroll
            for (int nf = 0; nf < 4; nf++) o[m][nf] = zz;
        }

        *(ushort8*)&Ks[srow][soff]     = *(const ushort8*)&K[(size_t)srow * HD + soff];
        *(ushort8*)&Ks[srow][soff + 8] = *(const ushort8*)&K[(size_t)srow * HD + soff + 8];
        *(ushort8*)&Vs[srow][soff]     = *(const ushort8*)&V[(size_t)srow * SS + soff];
        *(ushort8*)&Vs[srow][soff + 8] = *(const ushort8*)&V[(size_t)srow * SS + soff + 8];
        __syncthreads();

        for (int j0 = 0; j0 < jend; j0 += 64) {
            const bool havenext = (j0 + 64 < jend);
            ushort8 kn0, kn1, vn0, vn1;
            if (havenext) {
                kn0 = *(const ushort8*)&K[(size_t)(j0 + 64 + srow) * HD + soff];
                kn1 = *(const ushort8*)&K[(size_t)(j0 + 64 + srow) * HD + soff + 8];
                vn0 = *(const ushort8*)&V[(size_t)srow * SS + j0 + 64 + soff];
                vn1 = *(const ushort8*)&V[(size_t)srow * SS + j0 + 64 + soff + 8];
            }

            if (j0 <= wq_max) {
                floatx4 sf[2][4];
#pragma unroll
                for (int kg = 0; kg < 4; kg++) {
                    bf16x8 kb0 = *(const bf16x8*)&Ks[kg * 16 + l15][quad * 8];
                    bf16x8 kb1 = *(const bf16x8*)&Ks[kg * 16 + l15][32 + quad * 8];
#pragma unroll
                    for (int m = 0; m < 2; m++) {
                        floatx4 s = zz;
                        s = __builtin_amdgcn_mfma_f32_16x16x32_bf16(qa[m][0], kb0, s, 0, 0, 0);
                        s = __builtin_amdgcn_mfma_f32_16x16x32_bf16(qa[m][1], kb1, s, 0, 0, 0);
                        sf[m][kg] = s;
                    }
                }

                float alpha_[2][4];
#pragma unroll
                for (int m = 0; m < 2; m++)
#pragma unroll
                    for (int i = 0; i < 4; i++) {
                        const int qrow = wrow0 + m * 16 + quad * 4 + i;
                        float pv4[4];
#pragma unroll
                        for (int kg = 0; kg < 4; kg++) {
                            const int key = j0 + kg * 16 + l15;
                            float s = sf[m][kg][i] * 0.125f;
                            if (key > qrow) s = -10000.0f;
                            pv4[kg] = s;
                        }
                        float t = fmaxf(fmaxf(pv4[0], pv4[1]), fmaxf(pv4[2], pv4[3]));
                        t = fmaxf(t, __shfl_xor(t, 1));
                        t = fmaxf(t, __shfl_xor(t, 2));
                        t = fmaxf(t, __shfl_xor(t, 4));
                        t = fmaxf(t, __shfl_xor(t, 8));
                        const float mnew = fmaxf(mrow[m][i], t);
                        alpha_[m][i] = __expf(mrow[m][i] - mnew);
                        mrow[m][i] = mnew;
                        ushortx4 pk;
#pragma unroll
                        for (int kg = 0; kg < 4; kg++)
                            pk[kg] = f2bf(__expf(pv4[kg] - mnew));
                        *(ushortx4*)&Pl[w][m * 16 + quad * 4 + i][l15 * 4] = pk;
                    }

#pragma unroll
                for (int m = 0; m < 2; m++) {
#pragma unroll
                    for (int i = 0; i < 4; i++) o5[m][i] *= alpha_[m][i];
#pragma unroll
                    for (int nf = 0; nf < 4; nf++)
#pragma unroll
                        for (int i = 0; i < 4; i++) o[m][nf][i] *= alpha_[m][i];
                }

                bf16x8 pa[2][2];
#pragma unroll
                for (int m = 0; m < 2; m++) {
                    pa[m][0] = *(const bf16x8*)&Pl[w][m * 16 + l15][quad * 8];
                    pa[m][1] = *(const bf16x8*)&Pl[w][m * 16 + l15][32 + quad * 8];
                }

#pragma unroll
                for (int m = 0; m < 2; m++) {
                    o5[m] = __builtin_amdgcn_mfma_f32_16x16x32_bf16(pa[m][0], ones, o5[m], 0, 0, 0);
                    o5[m] = __builtin_amdgcn_mfma_f32_16x16x32_bf16(pa[m][1], ones, o5[m], 0, 0, 0);
                }
#pragma unroll
                for (int nf = 0; nf < 4; nf++) {
                    bf16x8 vb0 = *(const bf16x8*)&Vs[nf * 16 + l15][quad * 8];
                    bf16x8 vb1 = *(const bf16x8*)&Vs[nf * 16 + l15][32 + quad * 8];
#pragma unroll
                    for (int m = 0; m < 2; m++) {
                        o[m][nf] = __builtin_amdgcn_mfma_f32_16x16x32_bf16(pa[m][0], vb0, o[m][nf], 0, 0, 0);
                        o[m][nf] = __builtin_amdgcn_mfma_f32_16x16x32_bf16(pa[m][1], vb1, o[m][nf], 0, 0, 0);
                    }
                }
            }
            __syncthreads();
            if (havenext) {
                *(ushort8*)&Ks[srow][soff]     = kn0;
                *(ushort8*)&Ks[srow][soff + 8] = kn1;
                *(ushort8*)&Vs[srow][soff]     = vn0;
                *(ushort8*)&Vs[srow][soff + 8] = vn1;
            }
            __syncthreads();
        }

#pragma unroll
        for (int m = 0; m < 2; m++)
#pragma unroll
            for (int nf = 0; nf < 4; nf++)
#pragma unroll
                for (int i = 0; i < 4; i++) {
                    const int s = wrow0 + m * 16 + quad * 4 + i;
                    amerged[(size_t)(b * SS + s) * NXX + h * HD + nf * 16 + l15] =
                        f2bf(o[m][nf][i] / o5[m][i]);
                }
        __syncthreads();
    }
}

extern "C" void kernel_launch(void* const* d_in, const int* in_sizes, int n_in,
                              void* d_out, int out_size, void* d_ws, size_t ws_size,
                              hipStream_t stream) {
    const void* x     = d_in[0];
    const void* Wqkv  = d_in[1];
    const void* bqkv  = d_in[2];
    const void* Wproj = d_in[3];
    const void* bproj = d_in[4];

    int* flag = (int*)d_ws;
    unsigned short* ws = (unsigned short*)d_ws + 8;
    unsigned short* WqkvT   = ws;                        // 3072*1024  (6 MB)
    unsigned short* WprojT  = WqkvT + 3072 * 1024;       // 1024*1024  (2 MB)
    unsigned short* q_ws    = WprojT + 1024 * 1024;      // 8M         (16 MB)
    unsigned short* kbf     = q_ws + 8 * 1024 * 1024;    // 8M         (16 MB)
    unsigned short* vbfT    = kbf + 8 * 1024 * 1024;     // 8M         (16 MB)
    unsigned short* amerged = vbfT + 8 * 1024 * 1024;    // 8M         (16 MB)
    unsigned short* xbf     = amerged;                   // ALIAS: xbf dead before attn writes amerged
    // total ws: ~72 MB

    sniff_k<<<1, 64, 0, stream>>>((const unsigned short*)x, flag);
    prep<<<dim3(8192), 256, 0, stream>>>(x, Wqkv, Wproj, xbf, WqkvT, WprojT, flag);
    gemm_bt<1><<<dim3(3072 / 128, 8192 / 128), 256, 0, stream>>>(
        xbf, WqkvT, bqkv, d_out, q_ws, kbf, 8192, 3072, 1024, flag);
    transpose_v<<<dim3(128 * 16), 256, 0, stream>>>(d_out, vbfT, flag);
    attn<<<dim3(BB * NH * 4), 256, 0, stream>>>(q_ws, kbf, vbfT, amerged);
    gemm_bt<0><<<dim3(1024 / 128, 8192 / 128), 256, 0, stream>>>(
        amerged, WprojT, bproj, d_out, nullptr, nullptr, 8192, 1024, 1024, flag);
}

// Round 3
// 346.744 us; speedup vs baseline: 1.1265x; 1.0354x over previous
//
#include <hip/hip_runtime.h>
#include <stdint.h>

// Problem: B=8, S=1024, NX=1024, H=16, D=64 (GPT-2 attention block)
// out = [ a: B*S*NX ][ present_k: B*H*S*D ][ present_v: B*H*S*D ]
// Input/output dtype sniffed at runtime (fp32 vs bf16); internals bf16.

#define BB 8
#define SS 1024
#define NXX 1024
#define NH 16
#define HD 64
#define KK 1024   // GEMM K (both GEMMs)
#define NKT 16    // K / 64

typedef __bf16 bf16x8 __attribute__((ext_vector_type(8)));
typedef float  floatx4 __attribute__((ext_vector_type(4)));
typedef unsigned short ushort8 __attribute__((ext_vector_type(8)));
typedef unsigned short ushortx4 __attribute__((ext_vector_type(4)));  // 'ushort4' collides with HIP builtin

__device__ inline float bf2f(unsigned short u) {
    unsigned int x = ((unsigned int)u) << 16;
    float f;
    __builtin_memcpy(&f, &x, 4);
    return f;
}
__device__ inline unsigned short f2bf(float f) {
    unsigned int u;
    __builtin_memcpy(&u, &f, 4);
    u += 0x7FFFu + ((u >> 16) & 1u);  // RNE
    return (unsigned short)(u >> 16);
}

// async global->LDS, 16B per lane (dest = wave-uniform base + lane*16)
__device__ inline void gload_lds16(const unsigned short* g, unsigned short* l) {
    __builtin_amdgcn_global_load_lds(
        (const __attribute__((address_space(1))) void*)g,
        (__attribute__((address_space(3))) void*)l, 16, 0, 0);
}

// raw barrier WITHOUT the vmcnt(0)/lgkmcnt(0) drain __syncthreads implies.
// sched_barrier + "memory" clobber = compiler fence both IR- and MI-level.
__device__ inline void barrier_raw() {
    asm volatile("" ::: "memory");
    __builtin_amdgcn_sched_barrier(0);
    __builtin_amdgcn_s_barrier();
    __builtin_amdgcn_sched_barrier(0);
    asm volatile("" ::: "memory");
}
#define WAIT_VM4() asm volatile("s_waitcnt vmcnt(4)" ::: "memory")
#define WAIT_VM0() asm volatile("s_waitcnt vmcnt(0)" ::: "memory")

// ---------------- dtype sniff: flag=1 if data is fp32, 0 if bf16 ----------------
__global__ void sniff_k(const unsigned short* __restrict__ x, int* __restrict__ flag) {
    if (threadIdx.x == 0 && blockIdx.x == 0) {
        int g = 0;
        for (int i = 0; i < 512; i++) {
            float f = bf2f(x[i]);
            float a = fabsf(f);
            if (!(a <= 1e4f)) g++;
            else if (f != 0.f && a < 1e-35f) g++;
        }
        *flag = (g > 16) ? 1 : 0;
    }
}

// ---------------- prep: convert_x + transpose(Wqkv) + transpose(Wproj) ----------
__global__ __launch_bounds__(256) void prep(
    const void* __restrict__ x, const void* __restrict__ Wqkv,
    const void* __restrict__ Wproj,
    unsigned short* __restrict__ xbf, unsigned short* __restrict__ WqkvT,
    unsigned short* __restrict__ WprojT, const int* __restrict__ flagp) {
    const int f32 = *flagp;
    int blk = blockIdx.x;
    if (blk < 4096) {
        const size_t i = ((size_t)blk * 256 + threadIdx.x) * 8;
        if (f32) {
            const floatx4* p = (const floatx4*)((const float*)x + i);
            floatx4 f0 = p[0], f1 = p[1];
            ushort8 u;
#pragma unroll
            for (int j = 0; j < 4; j++) { u[j] = f2bf(f0[j]); u[4 + j] = f2bf(f1[j]); }
            *(ushort8*)(xbf + i) = u;
        } else {
            *(ushort8*)(xbf + i) = *(const ushort8*)((const unsigned short*)x + i);
        }
        return;
    }
    blk -= 4096;
    const void* in;
    unsigned short* out;
    int R, C;
    if (blk < 3072) { in = Wqkv; out = WqkvT; R = 1024; C = 3072; }
    else            { blk -= 3072; in = Wproj; out = WprojT; R = 1024; C = 1024; }
    const int ctiles = C / 32;
    const int c0 = (blk % ctiles) * 32, r0 = (blk / ctiles) * 32;

    __shared__ unsigned short tile[32][33];
    const int tx = threadIdx.x & 31, ty = threadIdx.x >> 5;  // 32 x 8
    if (f32) {
        const float* inf = (const float*)in;
#pragma unroll
        for (int i = ty; i < 32; i += 8)
            tile[i][tx] = f2bf(inf[(size_t)(r0 + i) * C + c0 + tx]);
    } else {
        const unsigned short* inu = (const unsigned short*)in;
#pragma unroll
        for (int i = ty; i < 32; i += 8)
            tile[i][tx] = inu[(size_t)(r0 + i) * C + c0 + tx];
    }
    __syncthreads();
#pragma unroll
    for (int i = ty; i < 32; i += 8)
        out[(size_t)(c0 + i) * R + r0 + tx] = tile[tx][i];
}

// ---------------- transpose_v: vbfT[bh][d][sperm] <- d_out v region ------------
__global__ __launch_bounds__(256) void transpose_v(
    const void* __restrict__ outbase, unsigned short* __restrict__ vbfT,
    const int* __restrict__ flagp) {
    const int f32 = *flagp;
    const int blk = blockIdx.x;
    const int sb = blk & 15;       // which 64-s block
    const int bh = blk >> 4;       // 0..127
    const int tid = threadIdx.x;
    const int r = tid >> 2;          // s within 64-block
    const int c0 = (tid & 3) * 16;   // d start
    __shared__ unsigned short tile[64][72];
    const int perm = ((r & 15) << 2) | (r >> 4);
    const size_t esz = f32 ? 4 : 2;
    const char* vbase = (const char*)outbase + (size_t)(2 * BB * SS * NXX) * esz;
    if (f32) {
        const float* src = (const float*)vbase + ((size_t)bh * SS + sb * 64 + r) * HD + c0;
#pragma unroll
        for (int j = 0; j < 16; j++) tile[c0 + j][perm] = f2bf(src[j]);
    } else {
        const unsigned short* src = (const unsigned short*)vbase + ((size_t)bh * SS + sb * 64 + r) * HD + c0;
#pragma unroll
        for (int j = 0; j < 16; j++) tile[c0 + j][perm] = src[j];
    }
    __syncthreads();
    const int d = tid >> 2;
    const int o0 = (tid & 3) * 16;
    unsigned short* dst = vbfT + ((size_t)(bh * HD + d)) * SS + sb * 64 + o0;
    *(ushort8*)dst       = *(const ushort8*)&tile[d][o0];
    *(ushort8*)(dst + 8) = *(const ushort8*)&tile[d][o0 + 8];
}

// ---------------- GEMM 256x256x64, 8-phase counted-vmcnt (T1+T2+T3+T4+T5) -----
// A[M,K], Bt[N,K] bf16, K=1024. 512 threads = 8 waves (2 row-groups x 4 col-groups).
// LDS: per K-tile, A(256x64) and B(256x64) each as 2 halves of 128x64, double-
// buffered by K-tile parity = 128 KiB.
// Swizzle (rule #21, both-sides): LDS row off ^= (row&7)<<4 bytes; staged via
// pre-swizzled per-lane GLOBAL source (global_load_lds dest stays linear).
// Stage schedule during tile t (hazard-checked): q0:A0(t+1) q1:A1(t+1) (opposite
// slot, no collision) q2:B0(t+2) q3:B1(t+2) (same slot; B dead since q0, 2+
// barriers earlier). One vmcnt(4) per K-tile at q3 (vmcnt(0) only in K-tail).
#define STAGE_A(slot, h, kt) do { \
    const unsigned short* sg_ = Ab + (size_t)((h) * 128) * KK + (size_t)(kt) * 64; \
    gload_lds16(sg_, &As[slot][h][w * 512]); \
    gload_lds16(sg_ + (size_t)64 * KK, &As[slot][h][4096 + w * 512]); \
} while (0)
#define STAGE_B(slot, h, kt) do { \
    const unsigned short* sg_ = Bb + (size_t)((h) * 128) * KK + (size_t)(kt) * 64; \
    gload_lds16(sg_, &Bs[slot][h][w * 512]); \
    gload_lds16(sg_ + (size_t)64 * KK, &Bs[slot][h][4096 + w * 512]); \
} while (0)
#define PHASE(qq, STAGE_STMT, TAIL) do { \
    bf16x8 a_[2][2]; \
    _Pragma("unroll") \
    for (int mm = 0; mm < 2; mm++) { \
        const int arow = (qq) * 32 + mm * 16 + l15; \
        a_[mm][0] = *(const bf16x8*)&Ah[arow * 64 + fo0]; \
        a_[mm][1] = *(const bf16x8*)&Ah[arow * 64 + fo1]; \
    } \
    STAGE_STMT; \
    barrier_raw(); \
    __builtin_amdgcn_s_setprio(1); \
    _Pragma("unroll") \
    for (int mm = 0; mm < 2; mm++) \
    _Pragma("unroll") \
    for (int nf = 0; nf < 4; nf++) { \
        acc[2 * (qq) + mm][nf] = __builtin_amdgcn_mfma_f32_16x16x32_bf16(a_[mm][0], bfr[nf][0], acc[2 * (qq) + mm][nf], 0, 0, 0); \
        acc[2 * (qq) + mm][nf] = __builtin_amdgcn_mfma_f32_16x16x32_bf16(a_[mm][1], bfr[nf][1], acc[2 * (qq) + mm][nf], 0, 0, 0); \
    } \
    __builtin_amdgcn_s_setprio(0); \
    TAIL; \
    barrier_raw(); \
} while (0)

template <int MODE>
__global__ __launch_bounds__(512, 2) void gemm8p(
    const unsigned short* __restrict__ A,
    const unsigned short* __restrict__ Bt,
    const void* __restrict__ bias,
    void* __restrict__ outbase,
    unsigned short* __restrict__ q_ws,
    unsigned short* __restrict__ kbf,
    int M, int N, int Nt, const int* __restrict__ flagp) {
    __shared__ __align__(16) unsigned short As[2][2][128 * 64];
    __shared__ __align__(16) unsigned short Bs[2][2][128 * 64];

    const int f32 = *flagp;
    const int tid  = threadIdx.x;
    const int lane = tid & 63;
    const int w = tid >> 6;          // wave 0..7
    const int r = w >> 2;            // row group (A half) 0..1
    const int c = w & 3;             // col group 0..3
    const int bh2 = c >> 1;          // B half
    const int l15 = lane & 15;
    const int quad = lane >> 4;

    // XCD-aware bijective swizzle (gridDim.x % 8 == 0 for both launches)
    const int cpx = gridDim.x >> 3;
    const int bid = (blockIdx.x & 7) * cpx + (blockIdx.x >> 3);
    const int bx = bid % Nt, by = bid / Nt;
    const int row0 = by * 256, col0 = bx * 256;

    floatx4 acc[8][4];
    floatx4 zz = {0.f, 0.f, 0.f, 0.f};
#pragma unroll
    for (int i = 0; i < 8; i++)
#pragma unroll
        for (int j = 0; j < 4; j++) acc[i][j] = zz;

    // staging: thread covers row srow (0..63 per issue), 16B at swizzled col
    const int srow = tid >> 3;
    const int scole = ((tid & 7) ^ (srow & 7)) << 3;  // pre-swizzled col (elems)
    const unsigned short* Ab = A  + (size_t)(row0 + srow) * KK + scole;
    const unsigned short* Bb = Bt + (size_t)(col0 + srow) * KK + scole;

    // fragment read offsets (elems): (kh*32 + quad*8) ^ ((l15&7)*8)
    const int fo0 = (quad << 3) ^ ((l15 & 7) << 3);
    const int fo1 = fo0 ^ 32;

    // prologue: tile0 A+B, tile1 B. vmcnt(4) leaves B(1) in flight.
    STAGE_A(0, 0, 0); STAGE_A(0, 1, 0);
    STAGE_B(0, 0, 0); STAGE_B(0, 1, 0);
    STAGE_B(1, 0, 1); STAGE_B(1, 1, 1);
    WAIT_VM4();
    barrier_raw();

    bf16x8 bfr[4][2];
#pragma unroll 2
    for (int t = 0; t < NKT; t++) {
        const int slot = t & 1;
        const unsigned short* Ah = &As[slot][r][0];
        const unsigned short* Bh = &Bs[slot][bh2][0];
#pragma unroll
        for (int nf = 0; nf < 4; nf++) {
            const int brow = (c & 1) * 64 + nf * 16 + l15;
            bfr[nf][0] = *(const bf16x8*)&Bh[brow * 64 + fo0];
            bfr[nf][1] = *(const bf16x8*)&Bh[brow * 64 + fo1];
        }
        PHASE(0, { if (t + 1 < NKT) STAGE_A((t + 1) & 1, 0, t + 1); }, {});
        PHASE(1, { if (t + 1 < NKT) STAGE_A((t + 1) & 1, 1, t + 1); }, {});
        PHASE(2, { if (t + 2 < NKT) STAGE_B(slot, 0, t + 2); }, {});
        PHASE(3, { if (t + 2 < NKT) STAGE_B(slot, 1, t + 2); },
              { if (t < NKT - 2) { WAIT_VM4(); } else { WAIT_VM0(); } });
    }

    // ---------------- epilogue ----------------
    float bv[4];
#pragma unroll
    for (int nf = 0; nf < 4; nf++) {
        const int colb = col0 + c * 64 + nf * 16 + l15;
        bv[nf] = f32 ? ((const float*)bias)[colb] : bf2f(((const unsigned short*)bias)[colb]);
    }

    if (MODE == 0) {
#pragma unroll
        for (int mi = 0; mi < 8; mi++)
#pragma unroll
            for (int nf = 0; nf < 4; nf++) {
                const int colb = col0 + c * 64 + nf * 16 + l15;
#pragma unroll
                for (int i = 0; i < 4; i++) {
                    const int row = row0 + r * 128 + mi * 16 + quad * 4 + i;
                    const float val = acc[mi][nf][i] + bv[nf];
                    const size_t idx = (size_t)row * N + colb;
                    if (f32) ((float*)outbase)[idx] = val;
                    else     ((unsigned short*)outbase)[idx] = f2bf(val);
                }
            }
        return;
    }

    // MODE 1: section is block-uniform (256-col tile never straddles 1024)
    const int sec = col0 >> 10;
    const size_t esz = f32 ? 4 : 2;
    const int b = row0 >> 10;
    const int s0 = row0 & 1023;

    if (sec == 0) {
#pragma unroll
        for (int mi = 0; mi < 8; mi++)
#pragma unroll
            for (int nf = 0; nf < 4; nf++) {
                const int colb = col0 + c * 64 + nf * 16 + l15;
                const int h = (colb & 1023) >> 6, d = colb & 63;
#pragma unroll
                for (int i = 0; i < 4; i++) {
                    const int s = s0 + r * 128 + mi * 16 + quad * 4 + i;
                    q_ws[(size_t)((b * NH + h) * SS + s) * HD + d] = f2bf(acc[mi][nf][i] + bv[nf]);
                }
            }
    } else if (sec == 1) {
        char* kbase = (char*)outbase + (size_t)(BB * SS * NXX) * esz;
#pragma unroll
        for (int mi = 0; mi < 8; mi++)
#pragma unroll
            for (int nf = 0; nf < 4; nf++) {
                const int colb = col0 + c * 64 + nf * 16 + l15;
                const int h = (colb & 1023) >> 6, d = colb & 63;
#pragma unroll
                for (int i = 0; i < 4; i++) {
                    const int s = s0 + r * 128 + mi * 16 + quad * 4 + i;
                    const float val = acc[mi][nf][i] + bv[nf];
                    const size_t idx = (size_t)((b * NH + h) * SS + s) * HD + d;
                    if (f32) ((float*)kbase)[idx] = val;
                    else     ((unsigned short*)kbase)[idx] = f2bf(val);
                    kbf[idx] = f2bf(val);
                }
            }
    } else {
        char* vbase = (char*)outbase + (size_t)(2 * BB * SS * NXX) * esz;
#pragma unroll
        for (int mi = 0; mi < 8; mi++)
#pragma unroll
            for (int nf = 0; nf < 4; nf++) {
                const int colb = col0 + c * 64 + nf * 16 + l15;
                const int h = (colb & 1023) >> 6, d = colb & 63;
#pragma unroll
                for (int i = 0; i < 4; i++) {
                    const int s = s0 + r * 128 + mi * 16 + quad * 4 + i;
                    const float val = acc[mi][nf][i] + bv[nf];
                    const size_t idx = (size_t)((b * NH + h) * SS + s) * HD + d;
                    if (f32) ((float*)vbase)[idx] = val;
                    else     ((unsigned short*)vbase)[idx] = f2bf(val);
                }
            }
    }
}

// ---------------- flash attention: 4 waves/block, 2 paired Q-tiles/block ----------
// (unchanged from round 2 — LDS-staged K/V with register prefetch)
__global__ __launch_bounds__(256) void attn(
    const unsigned short* __restrict__ q_ws,
    const unsigned short* __restrict__ kbf,
    const unsigned short* __restrict__ vbfT,
    unsigned short* __restrict__ amerged) {
    const int tid = threadIdx.x;
    const int lane = tid & 63;
    const int w = tid >> 6;
    const int l15 = lane & 15, quad = lane >> 4;
    const int blk = blockIdx.x;
    const int p = blk & 3;               // tile pair: {p, 7-p}
    const int bh = blk >> 2;
    const int b = bh >> 4, h = bh & 15;

    const unsigned short* Q = q_ws + (size_t)bh * (SS * HD);
    const unsigned short* K = kbf + (size_t)bh * (SS * HD);
    const unsigned short* V = vbfT + (size_t)bh * (HD * SS);

    __shared__ __align__(16) unsigned short Ks[64][72];
    __shared__ __align__(16) unsigned short Vs[64][72];
    __shared__ __align__(16) unsigned short Pl[4][32][72];

    floatx4 zz = {0.f, 0.f, 0.f, 0.f};
    ushort8 ones_u;
#pragma unroll
    for (int j = 0; j < 8; j++) ones_u[j] = 0x3F80;  // bf16 1.0
    const bf16x8 ones = __builtin_bit_cast(bf16x8, ones_u);

    const int srow = tid >> 2;           // 0..63
    const int soff = (tid & 3) * 16;     // 0/16/32/48

#pragma unroll
    for (int tile = 0; tile < 2; tile++) {
        const int qb = tile ? (7 - p) : p;
        const int qbase = qb * 128;
        const int wrow0 = qbase + w * 32;
        const int wq_max = wrow0 + 31;
        const int jend = qbase + 128;

        bf16x8 qa[2][2];
#pragma unroll
        for (int m = 0; m < 2; m++)
#pragma unroll
            for (int t = 0; t < 2; t++)
                qa[m][t] = *(const bf16x8*)&Q[(size_t)(wrow0 + m * 16 + l15) * HD + t * 32 + quad * 8];

        floatx4 o[2][4], o5[2];
        float mrow[2][4];
#pragma unroll
        for (int m = 0; m < 2; m++) {
            o5[m] = zz;
#pragma unroll
            for (int i = 0; i < 4; i++) mrow[m][i] = -1e30f;
#pragma unroll
            for (int nf = 0; nf < 4; nf++) o[m][nf] = zz;
        }

        *(ushort8*)&Ks[srow][soff]     = *(const ushort8*)&K[(size_t)srow * HD + soff];
        *(ushort8*)&Ks[srow][soff + 8] = *(const ushort8*)&K[(size_t)srow * HD + soff + 8];
        *(ushort8*)&Vs[srow][soff]     = *(const ushort8*)&V[(size_t)srow * SS + soff];
        *(ushort8*)&Vs[srow][soff + 8] = *(const ushort8*)&V[(size_t)srow * SS + soff + 8];
        __syncthreads();

        for (int j0 = 0; j0 < jend; j0 += 64) {
            const bool havenext = (j0 + 64 < jend);
            ushort8 kn0, kn1, vn0, vn1;
            if (havenext) {
                kn0 = *(const ushort8*)&K[(size_t)(j0 + 64 + srow) * HD + soff];
                kn1 = *(const ushort8*)&K[(size_t)(j0 + 64 + srow) * HD + soff + 8];
                vn0 = *(const ushort8*)&V[(size_t)srow * SS + j0 + 64 + soff];
                vn1 = *(const ushort8*)&V[(size_t)srow * SS + j0 + 64 + soff + 8];
            }

            if (j0 <= wq_max) {
                floatx4 sf[2][4];
#pragma unroll
                for (int kg = 0; kg < 4; kg++) {
                    bf16x8 kb0 = *(const bf16x8*)&Ks[kg * 16 + l15][quad * 8];
                    bf16x8 kb1 = *(const bf16x8*)&Ks[kg * 16 + l15][32 + quad * 8];
#pragma unroll
                    for (int m = 0; m < 2; m++) {
                        floatx4 s = zz;
                        s = __builtin_amdgcn_mfma_f32_16x16x32_bf16(qa[m][0], kb0, s, 0, 0, 0);
                        s = __builtin_amdgcn_mfma_f32_16x16x32_bf16(qa[m][1], kb1, s, 0, 0, 0);
                        sf[m][kg] = s;
                    }
                }

                float alpha_[2][4];
#pragma unroll
                for (int m = 0; m < 2; m++)
#pragma unroll
                    for (int i = 0; i < 4; i++) {
                        const int qrow = wrow0 + m * 16 + quad * 4 + i;
                        float pv4[4];
#pragma unroll
                        for (int kg = 0; kg < 4; kg++) {
                            const int key = j0 + kg * 16 + l15;
                            float s = sf[m][kg][i] * 0.125f;
                            if (key > qrow) s = -10000.0f;
                            pv4[kg] = s;
                        }
                        float t = fmaxf(fmaxf(pv4[0], pv4[1]), fmaxf(pv4[2], pv4[3]));
                        t = fmaxf(t, __shfl_xor(t, 1));
                        t = fmaxf(t, __shfl_xor(t, 2));
                        t = fmaxf(t, __shfl_xor(t, 4));
                        t = fmaxf(t, __shfl_xor(t, 8));
                        const float mnew = fmaxf(mrow[m][i], t);
                        alpha_[m][i] = __expf(mrow[m][i] - mnew);
                        mrow[m][i] = mnew;
                        ushortx4 pk;
#pragma unroll
                        for (int kg = 0; kg < 4; kg++)
                            pk[kg] = f2bf(__expf(pv4[kg] - mnew));
                        *(ushortx4*)&Pl[w][m * 16 + quad * 4 + i][l15 * 4] = pk;
                    }

#pragma unroll
                for (int m = 0; m < 2; m++) {
#pragma unroll
                    for (int i = 0; i < 4; i++) o5[m][i] *= alpha_[m][i];
#pragma unroll
                    for (int nf = 0; nf < 4; nf++)
#pragma unroll
                        for (int i = 0; i < 4; i++) o[m][nf][i] *= alpha_[m][i];
                }

                bf16x8 pa[2][2];
#pragma unroll
                for (int m = 0; m < 2; m++) {
                    pa[m][0] = *(const bf16x8*)&Pl[w][m * 16 + l15][quad * 8];
                    pa[m][1] = *(const bf16x8*)&Pl[w][m * 16 + l15][32 + quad * 8];
                }

#pragma unroll
                for (int m = 0; m < 2; m++) {
                    o5[m] = __builtin_amdgcn_mfma_f32_16x16x32_bf16(pa[m][0], ones, o5[m], 0, 0, 0);
                    o5[m] = __builtin_amdgcn_mfma_f32_16x16x32_bf16(pa[m][1], ones, o5[m], 0, 0, 0);
                }
#pragma unroll
                for (int nf = 0; nf < 4; nf++) {
                    bf16x8 vb0 = *(const bf16x8*)&Vs[nf * 16 + l15][quad * 8];
                    bf16x8 vb1 = *(const bf16x8*)&Vs[nf * 16 + l15][32 + quad * 8];
#pragma unroll
                    for (int m = 0; m < 2; m++) {
                        o[m][nf] = __builtin_amdgcn_mfma_f32_16x16x32_bf16(pa[m][0], vb0, o[m][nf], 0, 0, 0);
                        o[m][nf] = __builtin_amdgcn_mfma_f32_16x16x32_bf16(pa[m][1], vb1, o[m][nf], 0, 0, 0);
                    }
                }
            }
            __syncthreads();
            if (havenext) {
                *(ushort8*)&Ks[srow][soff]     = kn0;
                *(ushort8*)&Ks[srow][soff + 8] = kn1;
                *(ushort8*)&Vs[srow][soff]     = vn0;
                *(ushort8*)&Vs[srow][soff + 8] = vn1;
            }
            __syncthreads();
        }

#pragma unroll
        for (int m = 0; m < 2; m++)
#pragma unroll
            for (int nf = 0; nf < 4; nf++)
#pragma unroll
                for (int i = 0; i < 4; i++) {
                    const int s = wrow0 + m * 16 + quad * 4 + i;
                    amerged[(size_t)(b * SS + s) * NXX + h * HD + nf * 16 + l15] =
                        f2bf(o[m][nf][i] / o5[m][i]);
                }
        __syncthreads();
    }
}

extern "C" void kernel_launch(void* const* d_in, const int* in_sizes, int n_in,
                              void* d_out, int out_size, void* d_ws, size_t ws_size,
                              hipStream_t stream) {
    const void* x     = d_in[0];
    const void* Wqkv  = d_in[1];
    const void* bqkv  = d_in[2];
    const void* Wproj = d_in[3];
    const void* bproj = d_in[4];

    int* flag = (int*)d_ws;
    unsigned short* ws = (unsigned short*)d_ws + 8;
    unsigned short* WqkvT   = ws;                        // 3072*1024  (6 MB)
    unsigned short* WprojT  = WqkvT + 3072 * 1024;       // 1024*1024  (2 MB)
    unsigned short* q_ws    = WprojT + 1024 * 1024;      // 8M         (16 MB)
    unsigned short* kbf     = q_ws + 8 * 1024 * 1024;    // 8M         (16 MB)
    unsigned short* vbfT    = kbf + 8 * 1024 * 1024;     // 8M         (16 MB)
    unsigned short* amerged = vbfT + 8 * 1024 * 1024;    // 8M         (16 MB)
    unsigned short* xbf     = amerged;                   // ALIAS: xbf dead before attn writes amerged
    // total ws: ~72 MB

    sniff_k<<<1, 64, 0, stream>>>((const unsigned short*)x, flag);
    prep<<<dim3(8192), 256, 0, stream>>>(x, Wqkv, Wproj, xbf, WqkvT, WprojT, flag);
    gemm8p<1><<<dim3(12 * 32), 512, 0, stream>>>(
        xbf, WqkvT, bqkv, d_out, q_ws, kbf, 8192, 3072, 12, flag);
    transpose_v<<<dim3(128 * 16), 256, 0, stream>>>(d_out, vbfT, flag);
    attn<<<dim3(BB * NH * 4), 256, 0, stream>>>(q_ws, kbf, vbfT, amerged);
    gemm8p<0><<<dim3(4 * 32), 512, 0, stream>>>(
        amerged, WprojT, bproj, d_out, nullptr, nullptr, 8192, 1024, 4, flag);
}

// Round 4
// 326.077 us; speedup vs baseline: 1.1979x; 1.0634x over previous
//
#include <hip/hip_runtime.h>
#include <stdint.h>

// Problem: B=8, S=1024, NX=1024, H=16, D=64 (GPT-2 attention block)
// out = [ a: B*S*NX ][ present_k: B*H*S*D ][ present_v: B*H*S*D ]
// Input/output dtype sniffed at runtime (fp32 vs bf16); internals bf16.

#define BB 8
#define SS 1024
#define NXX 1024
#define NH 16
#define HD 64
#define KK 1024   // GEMM K (both GEMMs)
#define NKT 16    // K / 64

typedef __bf16 bf16x8 __attribute__((ext_vector_type(8)));
typedef float  floatx4 __attribute__((ext_vector_type(4)));
typedef unsigned short ushort8 __attribute__((ext_vector_type(8)));
typedef unsigned short ushortx4 __attribute__((ext_vector_type(4)));  // 'ushort4' collides with HIP builtin

__device__ inline float bf2f(unsigned short u) {
    unsigned int x = ((unsigned int)u) << 16;
    float f;
    __builtin_memcpy(&f, &x, 4);
    return f;
}
__device__ inline unsigned short f2bf(float f) {
    unsigned int u;
    __builtin_memcpy(&u, &f, 4);
    u += 0x7FFFu + ((u >> 16) & 1u);  // RNE
    return (unsigned short)(u >> 16);
}

// async global->LDS, 16B per lane (dest = wave-uniform base + lane*16)
__device__ inline void gload_lds16(const unsigned short* g, unsigned short* l) {
    __builtin_amdgcn_global_load_lds(
        (const __attribute__((address_space(1))) void*)g,
        (__attribute__((address_space(3))) void*)l, 16, 0, 0);
}

// raw barrier WITHOUT the vmcnt(0)/lgkmcnt(0) drain __syncthreads implies.
__device__ inline void barrier_raw() {
    asm volatile("" ::: "memory");
    __builtin_amdgcn_sched_barrier(0);
    __builtin_amdgcn_s_barrier();
    __builtin_amdgcn_sched_barrier(0);
    asm volatile("" ::: "memory");
}
#define WAIT_VM0() asm volatile("s_waitcnt vmcnt(0)" ::: "memory")

// ---------------- dtype sniff: flag=1 if data is fp32, 0 if bf16 ----------------
// 1 wave, vectorized: 64 lanes x 8 elems = same 512 elements / predicate /
// threshold as before. (Old version: 1 thread x 512 serial scalar loads ~ tens
// of µs of whole-GPU latency.)
__global__ void sniff_k(const unsigned short* __restrict__ x, int* __restrict__ flag) {
    const int lane = threadIdx.x & 63;
    ushort8 v = *(const ushort8*)(x + (size_t)lane * 8);
    int g = 0;
#pragma unroll
    for (int j = 0; j < 8; j++) {
        float f = bf2f(v[j]);
        float a = fabsf(f);
        if (!(a <= 1e4f)) g++;
        else if (f != 0.f && a < 1e-35f) g++;
    }
#pragma unroll
    for (int s = 1; s < 64; s <<= 1) g += __shfl_xor(g, s);
    if (lane == 0 && blockIdx.x == 0) *flag = (g > 16) ? 1 : 0;
}

// ---------------- prep: convert_x + transpose(Wqkv) + transpose(Wproj) ----------
__global__ __launch_bounds__(256) void prep(
    const void* __restrict__ x, const void* __restrict__ Wqkv,
    const void* __restrict__ Wproj,
    unsigned short* __restrict__ xbf, unsigned short* __restrict__ WqkvT,
    unsigned short* __restrict__ WprojT, const int* __restrict__ flagp) {
    const int f32 = *flagp;
    int blk = blockIdx.x;
    if (blk < 4096) {
        const size_t i = ((size_t)blk * 256 + threadIdx.x) * 8;
        if (f32) {
            const floatx4* p = (const floatx4*)((const float*)x + i);
            floatx4 f0 = p[0], f1 = p[1];
            ushort8 u;
#pragma unroll
            for (int j = 0; j < 4; j++) { u[j] = f2bf(f0[j]); u[4 + j] = f2bf(f1[j]); }
            *(ushort8*)(xbf + i) = u;
        } else {
            *(ushort8*)(xbf + i) = *(const ushort8*)((const unsigned short*)x + i);
        }
        return;
    }
    blk -= 4096;
    const void* in;
    unsigned short* out;
    int R, C;
    if (blk < 3072) { in = Wqkv; out = WqkvT; R = 1024; C = 3072; }
    else            { blk -= 3072; in = Wproj; out = WprojT; R = 1024; C = 1024; }
    const int ctiles = C / 32;
    const int c0 = (blk % ctiles) * 32, r0 = (blk / ctiles) * 32;

    __shared__ unsigned short tile[32][33];
    const int tx = threadIdx.x & 31, ty = threadIdx.x >> 5;  // 32 x 8
    if (f32) {
        const float* inf = (const float*)in;
#pragma unroll
        for (int i = ty; i < 32; i += 8)
            tile[i][tx] = f2bf(inf[(size_t)(r0 + i) * C + c0 + tx]);
    } else {
        const unsigned short* inu = (const unsigned short*)in;
#pragma unroll
        for (int i = ty; i < 32; i += 8)
            tile[i][tx] = inu[(size_t)(r0 + i) * C + c0 + tx];
    }
    __syncthreads();
#pragma unroll
    for (int i = ty; i < 32; i += 8)
        out[(size_t)(c0 + i) * R + r0 + tx] = tile[tx][i];
}

// ---------------- transpose_v: vbfT[bh][d][sperm] <- d_out v region ------------
__global__ __launch_bounds__(256) void transpose_v(
    const void* __restrict__ outbase, unsigned short* __restrict__ vbfT,
    const int* __restrict__ flagp) {
    const int f32 = *flagp;
    const int blk = blockIdx.x;
    const int sb = blk & 15;       // which 64-s block
    const int bh = blk >> 4;       // 0..127
    const int tid = threadIdx.x;
    const int r = tid >> 2;          // s within 64-block
    const int c0 = (tid & 3) * 16;   // d start
    __shared__ unsigned short tile[64][72];
    const int perm = ((r & 15) << 2) | (r >> 4);
    const size_t esz = f32 ? 4 : 2;
    const char* vbase = (const char*)outbase + (size_t)(2 * BB * SS * NXX) * esz;
    if (f32) {
        const float* src = (const float*)vbase + ((size_t)bh * SS + sb * 64 + r) * HD + c0;
#pragma unroll
        for (int j = 0; j < 16; j++) tile[c0 + j][perm] = f2bf(src[j]);
    } else {
        const unsigned short* src = (const unsigned short*)vbase + ((size_t)bh * SS + sb * 64 + r) * HD + c0;
#pragma unroll
        for (int j = 0; j < 16; j++) tile[c0 + j][perm] = src[j];
    }
    __syncthreads();
    const int d = tid >> 2;
    const int o0 = (tid & 3) * 16;
    unsigned short* dst = vbfT + ((size_t)(bh * HD + d)) * SS + sb * 64 + o0;
    *(ushort8*)dst       = *(const ushort8*)&tile[d][o0];
    *(ushort8*)(dst + 8) = *(const ushort8*)&tile[d][o0 + 8];
}

// ---------------- GEMM 256xBN x64, 8-phase counted-vmcnt, phase-ahead reads ----
// BN = 64*NF. QKV: NF=3 -> grid 16x32=512 (2 exact rounds). proj: NF=2 ->
// grid 8x32=256 (1 exact round). 512 threads = 8 waves (2 row x 4 col groups).
// LDS: A 2x[256][64] dbuf (64K) + B 2x[BN][64] dbuf (NF*16K).
// T2 swizzle both-sides (rule #21): linear LDS dest, pre-swizzled global src,
// XOR'd fragment reads. Per-phase A-fragment reads issued ONE PHASE AHEAD
// (aX/aY named sets, static indexing) so MFMA never waits on reads issued in
// its own phase (except phase 0's B-burst).
// Stage schedule tile t: q0/q1: A halves (t+1, opposite slot); q2/q3: B chunks
// (t+2, same slot -- B reads complete by phase 1's lgkm wait, in-order lgkm).
// vmcnt(NF) per tile (drain A(t+1), leave B(t+2) in flight); vmcnt(0) in tail.
#define STAGE_A(slot, h, kt) do { \
    const unsigned short* sg_ = Ab + (size_t)((h) * 128) * KK + (size_t)(kt) * 64; \
    gload_lds16(sg_, &As[slot][(h) * 8192 + w * 512]); \
    gload_lds16(sg_ + (size_t)64 * KK, &As[slot][(h) * 8192 + 4096 + w * 512]); \
} while (0)
#define STAGE_B(slot, j, kt) do { \
    const unsigned short* sg_ = Bb + (size_t)((j) * 64) * KK + (size_t)(kt) * 64; \
    gload_lds16(sg_, &Bs[slot][(j) * 4096 + w * 512]); \
} while (0)
#define LOADA(dst, qq) do { \
    _Pragma("unroll") \
    for (int mm = 0; mm < 2; mm++) { \
        const int arow = (qq) * 32 + mm * 16 + l15; \
        dst[mm][0] = *(const bf16x8*)&Ah[arow * 64 + fo0]; \
        dst[mm][1] = *(const bf16x8*)&Ah[arow * 64 + fo1]; \
    } \
} while (0)
#define MFMAQ(qq, ar) do { \
    __builtin_amdgcn_s_setprio(1); \
    _Pragma("unroll") \
    for (int mm = 0; mm < 2; mm++) \
    _Pragma("unroll") \
    for (int nf = 0; nf < NF; nf++) { \
        acc[2 * (qq) + mm][nf] = __builtin_amdgcn_mfma_f32_16x16x32_bf16(ar[mm][0], bfr[nf][0], acc[2 * (qq) + mm][nf], 0, 0, 0); \
        acc[2 * (qq) + mm][nf] = __builtin_amdgcn_mfma_f32_16x16x32_bf16(ar[mm][1], bfr[nf][1], acc[2 * (qq) + mm][nf], 0, 0, 0); \
    } \
    __builtin_amdgcn_s_setprio(0); \
} while (0)
#define WAIT_VMNF() do { \
    if constexpr (NF == 2)      asm volatile("s_waitcnt vmcnt(2)" ::: "memory"); \
    else if constexpr (NF == 3) asm volatile("s_waitcnt vmcnt(3)" ::: "memory"); \
    else                        asm volatile("s_waitcnt vmcnt(4)" ::: "memory"); \
} while (0)

template <int MODE, int NF>
__global__ __launch_bounds__(512, 2) void gemm8p(
    const unsigned short* __restrict__ A,
    const unsigned short* __restrict__ Bt,
    const void* __restrict__ bias,
    void* __restrict__ outbase,
    unsigned short* __restrict__ q_ws,
    unsigned short* __restrict__ kbf,
    int N, int Nt, const int* __restrict__ flagp) {
    __shared__ __align__(16) unsigned short As[2][2 * 8192];
    __shared__ __align__(16) unsigned short Bs[2][NF * 4096];

    const int f32 = *flagp;
    const int tid  = threadIdx.x;
    const int lane = tid & 63;
    const int w = tid >> 6;          // wave 0..7
    const int r = w >> 2;            // row group (A half) 0..1
    const int c = w & 3;             // col group 0..3
    const int l15 = lane & 15;
    const int quad = lane >> 4;

    // XCD-aware bijective swizzle (gridDim.x % 8 == 0 for both launches)
    const int cpx = gridDim.x >> 3;
    const int bid = (blockIdx.x & 7) * cpx + (blockIdx.x >> 3);
    const int bx = bid % Nt, by = bid / Nt;
    const int row0 = by * 256, col0 = bx * (64 * NF);

    floatx4 acc[8][NF];
    floatx4 zz = {0.f, 0.f, 0.f, 0.f};
#pragma unroll
    for (int i = 0; i < 8; i++)
#pragma unroll
        for (int j = 0; j < NF; j++) acc[i][j] = zz;

    // staging: thread covers row srow (0..63 per chunk), 16B at pre-swizzled col
    const int srow = tid >> 3;
    const int scole = ((tid & 7) ^ (srow & 7)) << 3;
    const unsigned short* Ab = A  + (size_t)(row0 + srow) * KK + scole;
    const unsigned short* Bb = Bt + (size_t)(col0 + srow) * KK + scole;

    // fragment read offsets (elems): (kh*32 + quad*8) ^ ((row&7)*8)
    const int fo0 = (quad << 3) ^ ((l15 & 7) << 3);
    const int fo1 = fo0 ^ 32;

    // prologue: tile0 A+B, tile1 B. vmcnt(NF) leaves B(1) in flight.
    STAGE_A(0, 0, 0); STAGE_A(0, 1, 0);
#pragma unroll
    for (int j = 0; j < NF; j++) STAGE_B(0, j, 0);
#pragma unroll
    for (int j = 0; j < NF; j++) STAGE_B(1, j, 1);
    WAIT_VMNF();
    barrier_raw();

    bf16x8 bfr[NF][2], aX[2][2], aY[2][2];
#pragma unroll 2
    for (int t = 0; t < NKT; t++) {
        const int slot = t & 1;
        const unsigned short* Ah = &As[slot][r * 8192];
        const unsigned short* Bh = &Bs[slot][0];
#pragma unroll
        for (int nf = 0; nf < NF; nf++) {
            const int brow = c * (16 * NF) + nf * 16 + l15;
            bfr[nf][0] = *(const bf16x8*)&Bh[brow * 64 + fo0];
            bfr[nf][1] = *(const bf16x8*)&Bh[brow * 64 + fo1];
        }
        LOADA(aX, 0);
        // phase 0
        LOADA(aY, 1);
        if (t + 1 < NKT) STAGE_A(slot ^ 1, 0, t + 1);
        barrier_raw();
        MFMAQ(0, aX);
        barrier_raw();
        // phase 1
        LOADA(aX, 2);
        if (t + 1 < NKT) STAGE_A(slot ^ 1, 1, t + 1);
        barrier_raw();
        MFMAQ(1, aY);
        barrier_raw();
        // phase 2
        LOADA(aY, 3);
        if (t + 2 < NKT) {
#pragma unroll
            for (int j = 0; j < (NF + 1) / 2; j++) STAGE_B(slot, j, t + 2);
        }
        barrier_raw();
        MFMAQ(2, aX);
        barrier_raw();
        // phase 3
        if (t + 2 < NKT) {
#pragma unroll
            for (int j = (NF + 1) / 2; j < NF; j++) STAGE_B(slot, j, t + 2);
        }
        barrier_raw();
        MFMAQ(3, aY);
        if (t < NKT - 2) { WAIT_VMNF(); } else { WAIT_VM0(); }
        barrier_raw();
    }

    // ---------------- epilogue ----------------
    float bv[NF];
#pragma unroll
    for (int nf = 0; nf < NF; nf++) {
        const int colb = col0 + c * (16 * NF) + nf * 16 + l15;
        bv[nf] = f32 ? ((const float*)bias)[colb] : bf2f(((const unsigned short*)bias)[colb]);
    }

    if (MODE == 0) {
#pragma unroll
        for (int nf = 0; nf < NF; nf++) {
            const int colb = col0 + c * (16 * NF) + nf * 16 + l15;
#pragma unroll
            for (int mi = 0; mi < 8; mi++)
#pragma unroll
                for (int i = 0; i < 4; i++) {
                    const int row = row0 + r * 128 + mi * 16 + quad * 4 + i;
                    const float val = acc[mi][nf][i] + bv[nf];
                    const size_t idx = (size_t)row * N + colb;
                    if (f32) ((float*)outbase)[idx] = val;
                    else     ((unsigned short*)outbase)[idx] = f2bf(val);
                }
        }
        return;
    }

    // MODE 1: section resolved PER-NF (BN=192 tiles straddle 1024 boundaries;
    // 16-col fragments never do, so sec is wave-uniform per nf).
    const size_t esz = f32 ? 4 : 2;
    const int b = row0 >> 10;
    const int s0 = row0 & 1023;

#pragma unroll
    for (int nf = 0; nf < NF; nf++) {
        const int colb = col0 + c * (16 * NF) + nf * 16 + l15;
        const int sec = colb >> 10;
        const int h = (colb & 1023) >> 6, d = colb & 63;
        if (sec == 0) {
#pragma unroll
            for (int mi = 0; mi < 8; mi++)
#pragma unroll
                for (int i = 0; i < 4; i++) {
                    const int s = s0 + r * 128 + mi * 16 + quad * 4 + i;
                    q_ws[(size_t)((b * NH + h) * SS + s) * HD + d] = f2bf(acc[mi][nf][i] + bv[nf]);
                }
        } else if (sec == 1) {
            char* kbase = (char*)outbase + (size_t)(BB * SS * NXX) * esz;
#pragma unroll
            for (int mi = 0; mi < 8; mi++)
#pragma unroll
                for (int i = 0; i < 4; i++) {
                    const int s = s0 + r * 128 + mi * 16 + quad * 4 + i;
                    const float val = acc[mi][nf][i] + bv[nf];
                    const size_t idx = (size_t)((b * NH + h) * SS + s) * HD + d;
                    if (f32) ((float*)kbase)[idx] = val;
                    else     ((unsigned short*)kbase)[idx] = f2bf(val);
                    kbf[idx] = f2bf(val);
                }
        } else {
            char* vbase = (char*)outbase + (size_t)(2 * BB * SS * NXX) * esz;
#pragma unroll
            for (int mi = 0; mi < 8; mi++)
#pragma unroll
                for (int i = 0; i < 4; i++) {
                    const int s = s0 + r * 128 + mi * 16 + quad * 4 + i;
                    const float val = acc[mi][nf][i] + bv[nf];
                    const size_t idx = (size_t)((b * NH + h) * SS + s) * HD + d;
                    if (f32) ((float*)vbase)[idx] = val;
                    else     ((unsigned short*)vbase)[idx] = f2bf(val);
                }
        }
    }
}

// ---------------- flash attention: 4 waves/block, 2 paired Q-tiles/block ----------
// (unchanged from round 2/3 — LDS-staged K/V with register prefetch)
__global__ __launch_bounds__(256) void attn(
    const unsigned short* __restrict__ q_ws,
    const unsigned short* __restrict__ kbf,
    const unsigned short* __restrict__ vbfT,
    unsigned short* __restrict__ amerged) {
    const int tid = threadIdx.x;
    const int lane = tid & 63;
    const int w = tid >> 6;
    const int l15 = lane & 15, quad = lane >> 4;
    const int blk = blockIdx.x;
    const int p = blk & 3;               // tile pair: {p, 7-p}
    const int bh = blk >> 2;
    const int b = bh >> 4, h = bh & 15;

    const unsigned short* Q = q_ws + (size_t)bh * (SS * HD);
    const unsigned short* K = kbf + (size_t)bh * (SS * HD);
    const unsigned short* V = vbfT + (size_t)bh * (HD * SS);

    __shared__ __align__(16) unsigned short Ks[64][72];
    __shared__ __align__(16) unsigned short Vs[64][72];
    __shared__ __align__(16) unsigned short Pl[4][32][72];

    floatx4 zz = {0.f, 0.f, 0.f, 0.f};
    ushort8 ones_u;
#pragma unroll
    for (int j = 0; j < 8; j++) ones_u[j] = 0x3F80;  // bf16 1.0
    const bf16x8 ones = __builtin_bit_cast(bf16x8, ones_u);

    const int srow = tid >> 2;           // 0..63
    const int soff = (tid & 3) * 16;     // 0/16/32/48

#pragma unroll
    for (int tile = 0; tile < 2; tile++) {
        const int qb = tile ? (7 - p) : p;
        const int qbase = qb * 128;
        const int wrow0 = qbase + w * 32;
        const int wq_max = wrow0 + 31;
        const int jend = qbase + 128;

        bf16x8 qa[2][2];
#pragma unroll
        for (int m = 0; m < 2; m++)
#pragma unroll
            for (int t = 0; t < 2; t++)
                qa[m][t] = *(const bf16x8*)&Q[(size_t)(wrow0 + m * 16 + l15) * HD + t * 32 + quad * 8];

        floatx4 o[2][4], o5[2];
        float mrow[2][4];
#pragma unroll
        for (int m = 0; m < 2; m++) {
            o5[m] = zz;
#pragma unroll
            for (int i = 0; i < 4; i++) mrow[m][i] = -1e30f;
#pragma unroll
            for (int nf = 0; nf < 4; nf++) o[m][nf] = zz;
        }

        *(ushort8*)&Ks[srow][soff]     = *(const ushort8*)&K[(size_t)srow * HD + soff];
        *(ushort8*)&Ks[srow][soff + 8] = *(const ushort8*)&K[(size_t)srow * HD + soff + 8];
        *(ushort8*)&Vs[srow][soff]     = *(const ushort8*)&V[(size_t)srow * SS + soff];
        *(ushort8*)&Vs[srow][soff + 8] = *(const ushort8*)&V[(size_t)srow * SS + soff + 8];
        __syncthreads();

        for (int j0 = 0; j0 < jend; j0 += 64) {
            const bool havenext = (j0 + 64 < jend);
            ushort8 kn0, kn1, vn0, vn1;
            if (havenext) {
                kn0 = *(const ushort8*)&K[(size_t)(j0 + 64 + srow) * HD + soff];
                kn1 = *(const ushort8*)&K[(size_t)(j0 + 64 + srow) * HD + soff + 8];
                vn0 = *(const ushort8*)&V[(size_t)srow * SS + j0 + 64 + soff];
                vn1 = *(const ushort8*)&V[(size_t)srow * SS + j0 + 64 + soff + 8];
            }

            if (j0 <= wq_max) {
                floatx4 sf[2][4];
#pragma unroll
                for (int kg = 0; kg < 4; kg++) {
                    bf16x8 kb0 = *(const bf16x8*)&Ks[kg * 16 + l15][quad * 8];
                    bf16x8 kb1 = *(const bf16x8*)&Ks[kg * 16 + l15][32 + quad * 8];
#pragma unroll
                    for (int m = 0; m < 2; m++) {
                        floatx4 s = zz;
                        s = __builtin_amdgcn_mfma_f32_16x16x32_bf16(qa[m][0], kb0, s, 0, 0, 0);
                        s = __builtin_amdgcn_mfma_f32_16x16x32_bf16(qa[m][1], kb1, s, 0, 0, 0);
                        sf[m][kg] = s;
                    }
                }

                float alpha_[2][4];
#pragma unroll
                for (int m = 0; m < 2; m++)
#pragma unroll
                    for (int i = 0; i < 4; i++) {
                        const int qrow = wrow0 + m * 16 + quad * 4 + i;
                        float pv4[4];
#pragma unroll
                        for (int kg = 0; kg < 4; kg++) {
                            const int key = j0 + kg * 16 + l15;
                            float s = sf[m][kg][i] * 0.125f;
                            if (key > qrow) s = -10000.0f;
                            pv4[kg] = s;
                        }
                        float t = fmaxf(fmaxf(pv4[0], pv4[1]), fmaxf(pv4[2], pv4[3]));
                        t = fmaxf(t, __shfl_xor(t, 1));
                        t = fmaxf(t, __shfl_xor(t, 2));
                        t = fmaxf(t, __shfl_xor(t, 4));
                        t = fmaxf(t, __shfl_xor(t, 8));
                        const float mnew = fmaxf(mrow[m][i], t);
                        alpha_[m][i] = __expf(mrow[m][i] - mnew);
                        mrow[m][i] = mnew;
                        ushortx4 pk;
#pragma unroll
                        for (int kg = 0; kg < 4; kg++)
                            pk[kg] = f2bf(__expf(pv4[kg] - mnew));
                        *(ushortx4*)&Pl[w][m * 16 + quad * 4 + i][l15 * 4] = pk;
                    }

#pragma unroll
                for (int m = 0; m < 2; m++) {
#pragma unroll
                    for (int i = 0; i < 4; i++) o5[m][i] *= alpha_[m][i];
#pragma unroll
                    for (int nf = 0; nf < 4; nf++)
#pragma unroll
                        for (int i = 0; i < 4; i++) o[m][nf][i] *= alpha_[m][i];
                }

                bf16x8 pa[2][2];
#pragma unroll
                for (int m = 0; m < 2; m++) {
                    pa[m][0] = *(const bf16x8*)&Pl[w][m * 16 + l15][quad * 8];
                    pa[m][1] = *(const bf16x8*)&Pl[w][m * 16 + l15][32 + quad * 8];
                }

#pragma unroll
                for (int m = 0; m < 2; m++) {
                    o5[m] = __builtin_amdgcn_mfma_f32_16x16x32_bf16(pa[m][0], ones, o5[m], 0, 0, 0);
                    o5[m] = __builtin_amdgcn_mfma_f32_16x16x32_bf16(pa[m][1], ones, o5[m], 0, 0, 0);
                }
#pragma unroll
                for (int nf = 0; nf < 4; nf++) {
                    bf16x8 vb0 = *(const bf16x8*)&Vs[nf * 16 + l15][quad * 8];
                    bf16x8 vb1 = *(const bf16x8*)&Vs[nf * 16 + l15][32 + quad * 8];
#pragma unroll
                    for (int m = 0; m < 2; m++) {
                        o[m][nf] = __builtin_amdgcn_mfma_f32_16x16x32_bf16(pa[m][0], vb0, o[m][nf], 0, 0, 0);
                        o[m][nf] = __builtin_amdgcn_mfma_f32_16x16x32_bf16(pa[m][1], vb1, o[m][nf], 0, 0, 0);
                    }
                }
            }
            __syncthreads();
            if (havenext) {
                *(ushort8*)&Ks[srow][soff]     = kn0;
                *(ushort8*)&Ks[srow][soff + 8] = kn1;
                *(ushort8*)&Vs[srow][soff]     = vn0;
                *(ushort8*)&Vs[srow][soff + 8] = vn1;
            }
            __syncthreads();
        }

#pragma unroll
        for (int m = 0; m < 2; m++)
#pragma unroll
            for (int nf = 0; nf < 4; nf++)
#pragma unroll
                for (int i = 0; i < 4; i++) {
                    const int s = wrow0 + m * 16 + quad * 4 + i;
                    amerged[(size_t)(b * SS + s) * NXX + h * HD + nf * 16 + l15] =
                        f2bf(o[m][nf][i] / o5[m][i]);
                }
        __syncthreads();
    }
}

extern "C" void kernel_launch(void* const* d_in, const int* in_sizes, int n_in,
                              void* d_out, int out_size, void* d_ws, size_t ws_size,
                              hipStream_t stream) {
    const void* x     = d_in[0];
    const void* Wqkv  = d_in[1];
    const void* bqkv  = d_in[2];
    const void* Wproj = d_in[3];
    const void* bproj = d_in[4];

    int* flag = (int*)d_ws;
    unsigned short* ws = (unsigned short*)d_ws + 8;
    unsigned short* WqkvT   = ws;                        // 3072*1024  (6 MB)
    unsigned short* WprojT  = WqkvT + 3072 * 1024;       // 1024*1024  (2 MB)
    unsigned short* q_ws    = WprojT + 1024 * 1024;      // 8M         (16 MB)
    unsigned short* kbf     = q_ws + 8 * 1024 * 1024;    // 8M         (16 MB)
    unsigned short* vbfT    = kbf + 8 * 1024 * 1024;     // 8M         (16 MB)
    unsigned short* amerged = vbfT + 8 * 1024 * 1024;    // 8M         (16 MB)
    unsigned short* xbf     = amerged;                   // ALIAS: xbf dead before attn writes amerged
    // total ws: ~72 MB

    sniff_k<<<1, 64, 0, stream>>>((const unsigned short*)x, flag);
    prep<<<dim3(8192), 256, 0, stream>>>(x, Wqkv, Wproj, xbf, WqkvT, WprojT, flag);
    // QKV: BN=192 -> 16 x 32 = 512 blocks (2 exact rounds at 1 block/CU)
    gemm8p<1, 3><<<dim3(512), 512, 0, stream>>>(
        xbf, WqkvT, bqkv, d_out, q_ws, kbf, 3072, 16, flag);
    transpose_v<<<dim3(128 * 16), 256, 0, stream>>>(d_out, vbfT, flag);
    attn<<<dim3(BB * NH * 4), 256, 0, stream>>>(q_ws, kbf, vbfT, amerged);
    // proj: BN=128 -> 8 x 32 = 256 blocks (1 exact round)
    gemm8p<0, 2><<<dim3(256), 512, 0, stream>>>(
        amerged, WprojT, bproj, d_out, nullptr, nullptr, 1024, 8, flag);
}